// Round 1
// baseline (1332.437 us; speedup 1.0000x reference)
//
#include <hip/hip_runtime.h>

#define N_NODES 100000
#define N_EDGES 1600000
#define DIM 64
#define NEG_SLOPE 0.2f

__device__ __forceinline__ float elu_f(float v) {
    return v > 0.f ? v : (__expf(v) - 1.f);
}

__device__ __forceinline__ float leaky_f(float v) {
    return v > 0.f ? v : NEG_SLOPE * v;
}

// ---- K1: raw in-degree count (no self loops) ----
__global__ void __launch_bounds__(256) k_degree(const int* __restrict__ dst,
                                                int* __restrict__ ncnt, int E) {
    int i = blockIdx.x * blockDim.x + threadIdx.x;
    int stride = gridDim.x * blockDim.x;
    for (; i < E; i += stride) {
        atomicAdd(&ncnt[dst[i]], 1);
    }
}

// ---- K2b: dinv = rsqrt(indeg + 1) ----
__global__ void __launch_bounds__(256) k_dinv(const int* __restrict__ ncnt,
                                              float* __restrict__ dinv, int N) {
    int i = blockIdx.x * blockDim.x + threadIdx.x;
    if (i < N) dinv[i] = rsqrtf((float)(ncnt[i] + 1));
}

// ---- K2: h_gcn = x@Wgcn, h_gat = x@Wgat, alpha_s = h_gat@a_src, alpha_d = h_gat@a_dst ----
__global__ void __launch_bounds__(256) k_node_gemm(
    const float* __restrict__ x, const float* __restrict__ Wg,
    const float* __restrict__ Wa, const float* __restrict__ a_src,
    const float* __restrict__ a_dst, float* __restrict__ h_gcn,
    float* __restrict__ h_gat, float* __restrict__ alpha_s,
    float* __restrict__ alpha_d, int N) {
    __shared__ float sWg[64 * 64];
    __shared__ float sWa[64 * 64];
    __shared__ float sas[64], sad[64];
    __shared__ float sx[4][64];

    for (int i = threadIdx.x; i < 64 * 64; i += 256) {
        sWg[i] = Wg[i];
        sWa[i] = Wa[i];
    }
    if (threadIdx.x < 64) {
        sas[threadIdx.x] = a_src[threadIdx.x];
        sad[threadIdx.x] = a_dst[threadIdx.x];
    }
    __syncthreads();

    const int lane = threadIdx.x & 63;
    const int rloc = threadIdx.x >> 6;

    for (int row0 = blockIdx.x * 4; row0 < N; row0 += gridDim.x * 4) {
        int row = row0 + rloc;
        if (row >= N) continue;
        float xv = x[(size_t)row * DIM + lane];
        sx[rloc][lane] = xv;  // same-wave LDS write/read: compiler inserts lgkmcnt wait
        float accg = 0.f, acca = 0.f;
#pragma unroll
        for (int k = 0; k < 64; k++) {
            float xk = sx[rloc][k];
            accg = fmaf(xk, sWg[k * 64 + lane], accg);
            acca = fmaf(xk, sWa[k * 64 + lane], acca);
        }
        h_gcn[(size_t)row * DIM + lane] = accg;
        h_gat[(size_t)row * DIM + lane] = acca;
        float ps = acca * sas[lane];
        float pd = acca * sad[lane];
#pragma unroll
        for (int off = 32; off; off >>= 1) {
            ps += __shfl_xor(ps, off, 64);
            pd += __shfl_xor(pd, off, 64);
        }
        if (lane == 0) {
            alpha_s[row] = ps;
            alpha_d[row] = pd;
        }
    }
}

// ---- K3: fused edge pass. wave per edge; lane = feature ----
__global__ void __launch_bounds__(256) k_edge(
    const int* __restrict__ src, const int* __restrict__ dst,
    const float* __restrict__ x, const float* __restrict__ h_gcn,
    const float* __restrict__ h_gat, const float* __restrict__ alpha_s,
    const float* __restrict__ alpha_d, const float* __restrict__ dinv,
    float* __restrict__ gcn_acc, float* __restrict__ gat_un,
    float* __restrict__ nsum, float* __restrict__ denom, int E) {
    const int lane = threadIdx.x & 63;
    const int wid = blockIdx.x * (blockDim.x >> 6) + (threadIdx.x >> 6);
    const int nw = gridDim.x * (blockDim.x >> 6);

    for (int e = wid; e < E; e += nw) {
        int s = src[e];
        int d = dst[e];
        float norm = dinv[s] * dinv[d];
        float ee = __expf(leaky_f(alpha_s[s] + alpha_d[d]));
        size_t so = (size_t)s * DIM + lane;
        size_t dof = (size_t)d * DIM + lane;
        atomicAdd(&nsum[dof], x[so]);
        atomicAdd(&gcn_acc[dof], norm * h_gcn[so]);
        atomicAdd(&gat_un[dof], ee * h_gat[so]);
        if (lane == 0) atomicAdd(&denom[d], ee);
    }
}

// ---- K4: finalize. sage/gin GEMMs + self-loop terms + elu + weighted sum ----
__global__ void __launch_bounds__(256) k_final(
    const float* __restrict__ x, const float* __restrict__ nsum,
    const int* __restrict__ ncnt, const float* __restrict__ gcn_acc,
    const float* __restrict__ h_gcn, const float* __restrict__ dinv,
    const float* __restrict__ gat_un, const float* __restrict__ h_gat,
    const float* __restrict__ alpha_s, const float* __restrict__ alpha_d,
    const float* __restrict__ denom, const float* __restrict__ Wss,
    const float* __restrict__ Wsn, const float* __restrict__ Wgin,
    const float* __restrict__ wts, float* __restrict__ out, int N) {
    __shared__ float sWss[64 * 64];
    __shared__ float sWsn[64 * 64];
    __shared__ float sWgin[64 * 64];
    __shared__ float sx[4][64];
    __shared__ float sn[4][64];

    for (int i = threadIdx.x; i < 64 * 64; i += 256) {
        sWss[i] = Wss[i];
        sWsn[i] = Wsn[i];
        sWgin[i] = Wgin[i];
    }
    __syncthreads();

    const int lane = threadIdx.x & 63;
    const int rloc = threadIdx.x >> 6;
    const float w0 = wts[0], w1 = wts[1], w2 = wts[2], w3 = wts[3];

    for (int row0 = blockIdx.x * 4; row0 < N; row0 += gridDim.x * 4) {
        int row = row0 + rloc;
        if (row >= N) continue;
        size_t ro = (size_t)row * DIM + lane;
        float xv = x[ro];
        float nv = nsum[ro];
        sx[rloc][lane] = xv;
        sn[rloc][lane] = nv;
        float icnt = 1.f / fmaxf((float)ncnt[row], 1.f);
        float sage = 0.f, gin = 0.f;
#pragma unroll
        for (int k = 0; k < 64; k++) {
            float xk = sx[rloc][k];
            float nk = sn[rloc][k];
            sage = fmaf(xk, sWss[k * 64 + lane], sage);
            sage = fmaf(nk * icnt, sWsn[k * 64 + lane], sage);
            gin = fmaf(xk + nk, sWgin[k * 64 + lane], gin);
        }
        float dv = dinv[row];
        float gcn = gcn_acc[ro] + dv * dv * h_gcn[ro];
        float ee = __expf(leaky_f(alpha_s[row] + alpha_d[row]));
        float den = denom[row] + ee;
        float gat = (gat_un[ro] + ee * h_gat[ro]) / den;
        out[ro] = w0 * elu_f(gcn) + w1 * elu_f(sage) + w2 * elu_f(gin) +
                  w3 * elu_f(gat);
    }
}

extern "C" void kernel_launch(void* const* d_in, const int* in_sizes, int n_in,
                              void* d_out, int out_size, void* d_ws,
                              size_t ws_size, hipStream_t stream) {
    const float* x = (const float*)d_in[0];
    const float* wts = (const float*)d_in[1];
    const int* ei = (const int*)d_in[2];  // int32 (jax x64 disabled)
    const int* src = ei;
    const int* dst = ei + N_EDGES;
    const float* Wgcn = (const float*)d_in[3];
    const float* Wss = (const float*)d_in[4];
    const float* Wsn = (const float*)d_in[5];
    const float* Wgin = (const float*)d_in[6];
    const float* Wgat = (const float*)d_in[7];
    const float* a_src = (const float*)d_in[8];
    const float* a_dst = (const float*)d_in[9];
    float* out = (float*)d_out;

    const size_t Nd = (size_t)N_NODES * DIM;
    float* ws = (float*)d_ws;
    float* gcn_acc = ws;               // [N,64]  (zeroed)
    float* gat_un = gcn_acc + Nd;      // [N,64]  (zeroed)
    float* nsum = gat_un + Nd;         // [N,64]  (zeroed)
    float* denom = nsum + Nd;          // [N]     (zeroed)
    int* ncnt = (int*)(denom + N_NODES);  // [N]  (zeroed)
    float* h_gcn = (float*)(ncnt + N_NODES);  // [N,64]
    float* h_gat = h_gcn + Nd;                // [N,64]
    float* alpha_s = h_gat + Nd;              // [N]
    float* alpha_d = alpha_s + N_NODES;       // [N]
    float* dinv = alpha_d + N_NODES;          // [N]

    size_t zbytes = (3 * Nd + 2 * (size_t)N_NODES) * sizeof(float);
    hipMemsetAsync(gcn_acc, 0, zbytes, stream);

    k_degree<<<4096, 256, 0, stream>>>(dst, ncnt, N_EDGES);
    k_node_gemm<<<2048, 256, 0, stream>>>(x, Wgcn, Wgat, a_src, a_dst, h_gcn,
                                          h_gat, alpha_s, alpha_d, N_NODES);
    k_dinv<<<(N_NODES + 255) / 256, 256, 0, stream>>>(ncnt, dinv, N_NODES);
    k_edge<<<16384, 256, 0, stream>>>(src, dst, x, h_gcn, h_gat, alpha_s,
                                      alpha_d, dinv, gcn_acc, gat_un, nsum,
                                      denom, N_EDGES);
    k_final<<<2048, 256, 0, stream>>>(x, nsum, ncnt, gcn_acc, h_gcn, dinv,
                                      gat_un, h_gat, alpha_s, alpha_d, denom,
                                      Wss, Wsn, Wgin, wts, out, N_NODES);
}

// Round 2
// 892.223 us; speedup vs baseline: 1.4934x; 1.4934x over previous
//
#include <hip/hip_runtime.h>

#define N_NODES 100000
#define N_EDGES 1600000
#define DIM 64
#define NEG_SLOPE 0.2f

__device__ __forceinline__ float elu_f(float v) {
    return v > 0.f ? v : (__expf(v) - 1.f);
}

__device__ __forceinline__ float leaky_f(float v) {
    return v > 0.f ? v : NEG_SLOPE * v;
}

// ---- K1: raw in-degree count (no self loops) ----
__global__ void __launch_bounds__(256) k_degree(const int* __restrict__ dst,
                                                int* __restrict__ ncnt, int E) {
    int i = blockIdx.x * blockDim.x + threadIdx.x;
    int stride = gridDim.x * blockDim.x;
    for (; i < E; i += stride) atomicAdd(&ncnt[dst[i]], 1);
}

// ---- K2: single-block exclusive scan of ncnt -> off (N+1 entries) ----
__global__ void __launch_bounds__(1024) k_scan(const int* __restrict__ ncnt,
                                               int* __restrict__ off, int N) {
    __shared__ int part[1024];
    const int tid = threadIdx.x;
    const int chunk = (N + 1023) / 1024;
    const int beg = tid * chunk;
    const int end = min(beg + chunk, N);
    int s = 0;
    for (int i = beg; i < end; i++) s += ncnt[i];
    part[tid] = s;
    __syncthreads();
    for (int d = 1; d < 1024; d <<= 1) {
        int v = (tid >= d) ? part[tid - d] : 0;
        __syncthreads();
        part[tid] += v;
        __syncthreads();
    }
    int run = part[tid] - s;  // exclusive prefix
    for (int i = beg; i < end; i++) {
        off[i] = run;
        run += ncnt[i];
    }
    if (tid == 1023) off[N] = part[1023];
}

// ---- K3: dinv = rsqrt(indeg + 1) packed into scal[2*i+1] ----
__global__ void __launch_bounds__(256) k_dinv(const int* __restrict__ ncnt,
                                              float* __restrict__ scal, int N) {
    int i = blockIdx.x * blockDim.x + threadIdx.x;
    if (i < N) scal[2 * i + 1] = rsqrtf((float)(ncnt[i] + 1));
}

// ---- K4: node GEMMs. big[n] = {x_row, h_gcn_row, h_gat_row}; scal[2n]=alpha_s; alpha_d ----
__global__ void __launch_bounds__(256) k_node_gemm(
    const float* __restrict__ x, const float* __restrict__ Wg,
    const float* __restrict__ Wa, const float* __restrict__ a_src,
    const float* __restrict__ a_dst, float* __restrict__ big,
    float* __restrict__ scal, float* __restrict__ alpha_d, int N) {
    __shared__ float sWg[64 * 64];
    __shared__ float sWa[64 * 64];
    __shared__ float sas[64], sad[64];
    __shared__ float sx[4][64];

    for (int i = threadIdx.x; i < 64 * 64; i += 256) {
        sWg[i] = Wg[i];
        sWa[i] = Wa[i];
    }
    if (threadIdx.x < 64) {
        sas[threadIdx.x] = a_src[threadIdx.x];
        sad[threadIdx.x] = a_dst[threadIdx.x];
    }
    __syncthreads();

    const int lane = threadIdx.x & 63;
    const int rloc = threadIdx.x >> 6;

    for (int row0 = blockIdx.x * 4; row0 < N; row0 += gridDim.x * 4) {
        int row = row0 + rloc;
        if (row >= N) continue;
        float xv = x[(size_t)row * DIM + lane];
        sx[rloc][lane] = xv;  // same-wave LDS, wave-synchronous
        float accg = 0.f, acca = 0.f;
#pragma unroll
        for (int k = 0; k < 64; k++) {
            float xk = sx[rloc][k];
            accg = fmaf(xk, sWg[k * 64 + lane], accg);
            acca = fmaf(xk, sWa[k * 64 + lane], acca);
        }
        float* row_out = big + (size_t)row * 192;
        row_out[lane] = xv;
        row_out[64 + lane] = accg;
        row_out[128 + lane] = acca;
        float ps = acca * sas[lane];
        float pd = acca * sad[lane];
#pragma unroll
        for (int offs = 32; offs; offs >>= 1) {
            ps += __shfl_xor(ps, offs, 64);
            pd += __shfl_xor(pd, offs, 64);
        }
        if (lane == 0) {
            scal[2 * row] = ps;
            alpha_d[row] = pd;
        }
    }
}

// ---- K5: scatter src indices into CSR order ----
__global__ void __launch_bounds__(256) k_scatter(const int* __restrict__ src,
                                                 const int* __restrict__ dst,
                                                 const int* __restrict__ off,
                                                 int* __restrict__ cur,
                                                 int* __restrict__ srt, int E) {
    int i = blockIdx.x * blockDim.x + threadIdx.x;
    int stride = gridDim.x * blockDim.x;
    for (; i < E; i += stride) {
        int d = dst[i];
        int pos = off[d] + atomicAdd(&cur[d], 1);
        srt[pos] = src[i];
    }
}

// ---- K6: gather + full finalize. wave per node, lane = feature ----
__global__ void __launch_bounds__(1024) k_gather(
    const float* __restrict__ big, const float* __restrict__ scal,
    const float* __restrict__ alpha_d, const int* __restrict__ off,
    const int* __restrict__ srt, const float* __restrict__ Wss,
    const float* __restrict__ Wsn, const float* __restrict__ Wgin,
    const float* __restrict__ wts, float* __restrict__ out, int N) {
    __shared__ float sWss[64 * 64];
    __shared__ float sWsn[64 * 64];
    __shared__ float sWgin[64 * 64];
    __shared__ float sxn[16][2][64];

    for (int i = threadIdx.x; i < 64 * 64; i += 1024) {
        sWss[i] = Wss[i];
        sWsn[i] = Wsn[i];
        sWgin[i] = Wgin[i];
    }
    __syncthreads();

    const int lane = threadIdx.x & 63;
    const int w = threadIdx.x >> 6;  // wave id in block (0..15)
    const int wid = blockIdx.x * 16 + w;
    const int nw = gridDim.x * 16;
    const float w0 = wts[0], w1 = wts[1], w2 = wts[2], w3 = wts[3];

    for (int n = wid; n < N; n += nw) {
        const int off0 = off[n];
        const int deg = off[n + 1] - off0;
        const float as_d = scal[2 * n];
        const float dinv_d = scal[2 * n + 1];
        const float ad_d = alpha_d[n];

        float acc_n = 0.f, acc_gcn = 0.f, acc_gat = 0.f, den = 0.f;

        for (int c0 = 0; c0 < deg; c0 += 64) {
            int idx = c0 + lane;
            int sl = 0;
            float ee_l = 0.f, nm_l = 0.f;
            if (idx < deg) {
                sl = srt[off0 + idx];
                float a_s = scal[2 * sl];
                float dv = scal[2 * sl + 1];
                ee_l = __expf(leaky_f(a_s + ad_d));
                nm_l = dv * dinv_d;
            }
            int jmax = min(64, deg - c0);
            for (int j = 0; j < jmax; j++) {
                int s = __shfl(sl, j, 64);
                float ee = __shfl(ee_l, j, 64);
                float nm = __shfl(nm_l, j, 64);
                const float* row = big + (size_t)s * 192;
                acc_n += row[lane];
                acc_gcn = fmaf(nm, row[64 + lane], acc_gcn);
                acc_gat = fmaf(ee, row[128 + lane], acc_gat);
                den += ee;
            }
        }

        // self-loop terms (GCN + GAT)
        const float* rowd = big + (size_t)n * 192;
        float xv = rowd[lane];
        float ee_s = __expf(leaky_f(as_d + ad_d));
        acc_gcn = fmaf(dinv_d * dinv_d, rowd[64 + lane], acc_gcn);
        acc_gat = fmaf(ee_s, rowd[128 + lane], acc_gat);
        den += ee_s;
        float gat = acc_gat / den;

        // SAGE / GIN GEMMs (cross-lane via per-wave LDS)
        sxn[w][0][lane] = xv;
        sxn[w][1][lane] = acc_n;
        float icnt = 1.f / fmaxf((float)deg, 1.f);
        float sage = 0.f, gin = 0.f;
#pragma unroll
        for (int k = 0; k < 64; k++) {
            float xk = sxn[w][0][k];
            float nk = sxn[w][1][k];
            sage = fmaf(xk, sWss[k * 64 + lane], sage);
            sage = fmaf(nk * icnt, sWsn[k * 64 + lane], sage);
            gin = fmaf(xk + nk, sWgin[k * 64 + lane], gin);
        }

        out[(size_t)n * DIM + lane] = w0 * elu_f(acc_gcn) + w1 * elu_f(sage) +
                                      w2 * elu_f(gin) + w3 * elu_f(gat);
    }
}

extern "C" void kernel_launch(void* const* d_in, const int* in_sizes, int n_in,
                              void* d_out, int out_size, void* d_ws,
                              size_t ws_size, hipStream_t stream) {
    const float* x = (const float*)d_in[0];
    const float* wts = (const float*)d_in[1];
    const int* ei = (const int*)d_in[2];  // int32 (jax x64 disabled)
    const int* src = ei;
    const int* dst = ei + N_EDGES;
    const float* Wgcn = (const float*)d_in[3];
    const float* Wss = (const float*)d_in[4];
    const float* Wsn = (const float*)d_in[5];
    const float* Wgin = (const float*)d_in[6];
    const float* Wgat = (const float*)d_in[7];
    const float* a_src = (const float*)d_in[8];
    const float* a_dst = (const float*)d_in[9];
    float* out = (float*)d_out;

    const size_t N = N_NODES;
    float* ws = (float*)d_ws;
    float* big = ws;                        // [N][3][64]
    float* scal = big + N * 192;            // [N][2] (alpha_s, dinv)
    float* alpha_d = scal + 2 * N;          // [N]
    int* srt = (int*)(alpha_d + N);         // [E]
    int* cur = srt + N_EDGES;               // [N]   (zeroed)
    int* ncnt = cur + N;                    // [N]   (zeroed)
    int* off = ncnt + N;                    // [N+1]

    hipMemsetAsync(cur, 0, 2 * N * sizeof(int), stream);  // cur + ncnt

    k_degree<<<2048, 256, 0, stream>>>(dst, ncnt, N_EDGES);
    k_scan<<<1, 1024, 0, stream>>>(ncnt, off, N_NODES);
    k_dinv<<<(N_NODES + 255) / 256, 256, 0, stream>>>(ncnt, scal, N_NODES);
    k_node_gemm<<<2048, 256, 0, stream>>>(x, Wgcn, Wgat, a_src, a_dst, big,
                                          scal, alpha_d, N_NODES);
    k_scatter<<<2048, 256, 0, stream>>>(src, dst, off, cur, srt, N_EDGES);
    k_gather<<<512, 1024, 0, stream>>>(big, scal, alpha_d, off, srt, Wss, Wsn,
                                       Wgin, wts, out, N_NODES);
}

// Round 3
// 812.799 us; speedup vs baseline: 1.6393x; 1.0977x over previous
//
#include <hip/hip_runtime.h>
#include <hip/hip_fp16.h>

#define N_NODES 100000
#define N_EDGES 1600000
#define DIM 64
#define NEG_SLOPE 0.2f

__device__ __forceinline__ float elu_f(float v) {
    return v > 0.f ? v : (__expf(v) - 1.f);
}

__device__ __forceinline__ float leaky_f(float v) {
    return v > 0.f ? v : NEG_SLOPE * v;
}

// ---- K1: raw in-degree count (no self loops) ----
__global__ void __launch_bounds__(256) k_degree(const int* __restrict__ dst,
                                                int* __restrict__ ncnt, int E) {
    int i = blockIdx.x * blockDim.x + threadIdx.x;
    int stride = gridDim.x * blockDim.x;
    for (; i < E; i += stride) atomicAdd(&ncnt[dst[i]], 1);
}

// ---- K2: single-block exclusive scan of ncnt -> off (N+1 entries) ----
__global__ void __launch_bounds__(1024) k_scan(const int* __restrict__ ncnt,
                                               int* __restrict__ off, int N) {
    __shared__ int part[1024];
    const int tid = threadIdx.x;
    const int chunk = (N + 1023) / 1024;
    const int beg = tid * chunk;
    const int end = min(beg + chunk, N);
    int s = 0;
    for (int i = beg; i < end; i++) s += ncnt[i];
    part[tid] = s;
    __syncthreads();
    for (int d = 1; d < 1024; d <<= 1) {
        int v = (tid >= d) ? part[tid - d] : 0;
        __syncthreads();
        part[tid] += v;
        __syncthreads();
    }
    int run = part[tid] - s;  // exclusive prefix
    for (int i = beg; i < end; i++) {
        off[i] = run;
        run += ncnt[i];
    }
    if (tid == 1023) off[N] = part[1023];
}

// ---- K3: dinv = rsqrt(indeg + 1) into scal2[i].y ----
__global__ void __launch_bounds__(256) k_dinv(const int* __restrict__ ncnt,
                                              float2* __restrict__ scal2,
                                              int N) {
    int i = blockIdx.x * blockDim.x + threadIdx.x;
    if (i < N) scal2[i].y = rsqrtf((float)(ncnt[i] + 1));
}

// ---- K4: node GEMMs. bigp[n*64+f] = f16x4{x, h_gcn, h_gat, 0}; scal2[n].x=alpha_s ----
__global__ void __launch_bounds__(256) k_node_gemm(
    const float* __restrict__ x, const float* __restrict__ Wg,
    const float* __restrict__ Wa, const float* __restrict__ a_src,
    const float* __restrict__ a_dst, uint2* __restrict__ bigp,
    float2* __restrict__ scal2, float* __restrict__ alpha_d, int N) {
    __shared__ float sWg[64 * 64];
    __shared__ float sWa[64 * 64];
    __shared__ float sas[64], sad[64];
    __shared__ float sx[4][64];

    for (int i = threadIdx.x; i < 64 * 64; i += 256) {
        sWg[i] = Wg[i];
        sWa[i] = Wa[i];
    }
    if (threadIdx.x < 64) {
        sas[threadIdx.x] = a_src[threadIdx.x];
        sad[threadIdx.x] = a_dst[threadIdx.x];
    }
    __syncthreads();

    const int lane = threadIdx.x & 63;
    const int rloc = threadIdx.x >> 6;

    for (int row0 = blockIdx.x * 4; row0 < N; row0 += gridDim.x * 4) {
        int row = row0 + rloc;
        if (row >= N) continue;
        float xv = x[(size_t)row * DIM + lane];
        sx[rloc][lane] = xv;  // same-wave LDS, wave-synchronous
        float accg = 0.f, acca = 0.f;
#pragma unroll
        for (int k = 0; k < 64; k++) {
            float xk = sx[rloc][k];
            accg = fmaf(xk, sWg[k * 64 + lane], accg);
            acca = fmaf(xk, sWa[k * 64 + lane], acca);
        }
        __half2 p0 = __floats2half2_rn(xv, accg);
        __half2 p1 = __floats2half2_rn(acca, 0.f);
        uint2 pk;
        pk.x = *(unsigned int*)&p0;
        pk.y = *(unsigned int*)&p1;
        bigp[(size_t)row * 64 + lane] = pk;

        float ps = acca * sas[lane];
        float pd = acca * sad[lane];
#pragma unroll
        for (int offs = 32; offs; offs >>= 1) {
            ps += __shfl_xor(ps, offs, 64);
            pd += __shfl_xor(pd, offs, 64);
        }
        if (lane == 0) {
            scal2[row].x = ps;
            alpha_d[row] = pd;
        }
    }
}

// ---- K5: scatter src indices into CSR order ----
__global__ void __launch_bounds__(256) k_scatter(const int* __restrict__ src,
                                                 const int* __restrict__ dst,
                                                 const int* __restrict__ off,
                                                 int* __restrict__ cur,
                                                 int* __restrict__ srt, int E) {
    int i = blockIdx.x * blockDim.x + threadIdx.x;
    int stride = gridDim.x * blockDim.x;
    for (; i < E; i += stride) {
        int d = dst[i];
        int pos = off[d] + atomicAdd(&cur[d], 1);
        srt[pos] = src[i];
    }
}

__device__ __forceinline__ void unpack_acc(uint2 q, float w, float ee,
                                           float nm, float& acc_n,
                                           float& acc_gcn, float& acc_gat) {
    __half2 a = *(__half2*)&q.x;  // {x, h_gcn}
    __half2 b = *(__half2*)&q.y;  // {h_gat, 0}
    float2 af = __half22float2(a);
    float2 bf = __half22float2(b);
    acc_n = fmaf(w, af.x, acc_n);
    acc_gcn = fmaf(nm, af.y, acc_gcn);
    acc_gat = fmaf(ee, bf.x, acc_gat);
}

// ---- K6: gather + full finalize. wave per node, lane = feature ----
__global__ void __launch_bounds__(1024) k_gather(
    const uint2* __restrict__ bigp, const float* __restrict__ x,
    const float2* __restrict__ scal2, const float* __restrict__ alpha_d,
    const int* __restrict__ off, const int* __restrict__ srt,
    const float* __restrict__ Wss, const float* __restrict__ Wsn,
    const float* __restrict__ Wgin, const float* __restrict__ wts,
    float* __restrict__ out, int N) {
    __shared__ float sWss[64 * 64];
    __shared__ float sWsn[64 * 64];
    __shared__ float sWgin[64 * 64];
    __shared__ float sxn[16][2][64];

    for (int i = threadIdx.x; i < 64 * 64; i += 1024) {
        sWss[i] = Wss[i];
        sWsn[i] = Wsn[i];
        sWgin[i] = Wgin[i];
    }
    __syncthreads();

    const int lane = threadIdx.x & 63;
    const int w = threadIdx.x >> 6;  // wave id in block (0..15)
    const int wid = blockIdx.x * 16 + w;
    const int nw = gridDim.x * 16;
    const float w0 = wts[0], w1 = wts[1], w2 = wts[2], w3 = wts[3];

    for (int n = wid; n < N; n += nw) {
        const int off0 = off[n];
        const int deg = off[n + 1] - off0;
        const float2 sc_d = scal2[n];
        const float as_d = sc_d.x;
        const float dinv_d = sc_d.y;
        const float ad_d = alpha_d[n];

        float acc_n = 0.f, acc_gcn = 0.f, acc_gat = 0.f, den = 0.f;

        for (int c0 = 0; c0 < deg; c0 += 64) {
            int idx = c0 + lane;
            int sl = 0;
            float ee_l = 0.f, nm_l = 0.f, w_l = 0.f;
            if (idx < deg) {
                sl = srt[off0 + idx];
                float2 sc = scal2[sl];
                ee_l = __expf(leaky_f(sc.x + ad_d));
                nm_l = sc.y * dinv_d;
                w_l = 1.f;
            }
            int jmax = min(64, deg - c0);
            // process 2 edges/iter; overruns (j+1>=jmax) carry zero weights
            for (int j = 0; j < jmax; j += 2) {
                int s0 = __shfl(sl, j, 64);
                float ee0 = __shfl(ee_l, j, 64);
                float nm0 = __shfl(nm_l, j, 64);
                float wt0 = __shfl(w_l, j, 64);
                int s1 = __shfl(sl, j + 1, 64);
                float ee1 = __shfl(ee_l, j + 1, 64);
                float nm1 = __shfl(nm_l, j + 1, 64);
                float wt1 = __shfl(w_l, j + 1, 64);
                uint2 q0 = bigp[(size_t)s0 * 64 + lane];
                uint2 q1 = bigp[(size_t)s1 * 64 + lane];
                unpack_acc(q0, wt0, ee0, nm0, acc_n, acc_gcn, acc_gat);
                unpack_acc(q1, wt1, ee1, nm1, acc_n, acc_gcn, acc_gat);
                den += ee0 + ee1;
            }
        }

        // self-loop terms (GCN + GAT); x self from f32 input
        uint2 qd = bigp[(size_t)n * 64 + lane];
        __half2 da = *(__half2*)&qd.x;
        __half2 db = *(__half2*)&qd.y;
        float hg_d = __half2float(da.y);
        float ha_d = __half2float(db.x);
        float xv = x[(size_t)n * DIM + lane];
        float ee_s = __expf(leaky_f(as_d + ad_d));
        acc_gcn = fmaf(dinv_d * dinv_d, hg_d, acc_gcn);
        acc_gat = fmaf(ee_s, ha_d, acc_gat);
        den += ee_s;
        float gat = acc_gat / den;

        // SAGE / GIN GEMMs (cross-lane via per-wave LDS)
        sxn[w][0][lane] = xv;
        sxn[w][1][lane] = acc_n;
        float icnt = 1.f / fmaxf((float)deg, 1.f);
        float sage = 0.f, gin = 0.f;
#pragma unroll
        for (int k = 0; k < 64; k++) {
            float xk = sxn[w][0][k];
            float nk = sxn[w][1][k];
            sage = fmaf(xk, sWss[k * 64 + lane], sage);
            sage = fmaf(nk * icnt, sWsn[k * 64 + lane], sage);
            gin = fmaf(xk + nk, sWgin[k * 64 + lane], gin);
        }

        out[(size_t)n * DIM + lane] = w0 * elu_f(acc_gcn) + w1 * elu_f(sage) +
                                      w2 * elu_f(gin) + w3 * elu_f(gat);
    }
}

extern "C" void kernel_launch(void* const* d_in, const int* in_sizes, int n_in,
                              void* d_out, int out_size, void* d_ws,
                              size_t ws_size, hipStream_t stream) {
    const float* x = (const float*)d_in[0];
    const float* wts = (const float*)d_in[1];
    const int* ei = (const int*)d_in[2];  // int32 (jax x64 disabled)
    const int* src = ei;
    const int* dst = ei + N_EDGES;
    const float* Wgcn = (const float*)d_in[3];
    const float* Wss = (const float*)d_in[4];
    const float* Wsn = (const float*)d_in[5];
    const float* Wgin = (const float*)d_in[6];
    const float* Wgat = (const float*)d_in[7];
    const float* a_src = (const float*)d_in[8];
    const float* a_dst = (const float*)d_in[9];
    float* out = (float*)d_out;

    const size_t N = N_NODES;
    char* ws = (char*)d_ws;
    uint2* bigp = (uint2*)ws;                      // [N*64] packed f16x4
    float2* scal2 = (float2*)(bigp + N * 64);      // [N] {alpha_s, dinv}
    float* alpha_d = (float*)(scal2 + N);          // [N]
    int* srt = (int*)(alpha_d + N);                // [E]
    int* cur = srt + N_EDGES;                      // [N] (zeroed)
    int* ncnt = cur + N;                           // [N] (zeroed)
    int* off = ncnt + N;                           // [N+1]

    hipMemsetAsync(cur, 0, 2 * N * sizeof(int), stream);  // cur + ncnt

    k_degree<<<2048, 256, 0, stream>>>(dst, ncnt, N_EDGES);
    k_scan<<<1, 1024, 0, stream>>>(ncnt, off, N_NODES);
    k_dinv<<<(N_NODES + 255) / 256, 256, 0, stream>>>(ncnt, scal2, N_NODES);
    k_node_gemm<<<2048, 256, 0, stream>>>(x, Wgcn, Wgat, a_src, a_dst, bigp,
                                          scal2, alpha_d, N_NODES);
    k_scatter<<<2048, 256, 0, stream>>>(src, dst, off, cur, srt, N_EDGES);
    k_gather<<<512, 1024, 0, stream>>>(bigp, x, scal2, alpha_d, off, srt, Wss,
                                       Wsn, Wgin, wts, out, N_NODES);
}

// Round 4
// 534.376 us; speedup vs baseline: 2.4934x; 1.5210x over previous
//
#include <hip/hip_runtime.h>
#include <hip/hip_fp16.h>

#define N_NODES 100000
#define N_EDGES 1600000
#define DIM 64
#define NEG_SLOPE 0.2f
#define SCAN_BLOCKS 128
#define SCAN_T 256

__device__ __forceinline__ float elu_f(float v) {
    return v > 0.f ? v : (__expf(v) - 1.f);
}

__device__ __forceinline__ float leaky_f(float v) {
    return v > 0.f ? v : NEG_SLOPE * v;
}

__device__ __forceinline__ int pad4(int v) { return (v + 3) & ~3; }

// ---- K1: degree count + per-edge slot (int4 vectorized) ----
__global__ void __launch_bounds__(256) k_degree(const int4* __restrict__ dst4,
                                                int* __restrict__ ncnt,
                                                int4* __restrict__ slot4,
                                                int E4) {
    int i = blockIdx.x * blockDim.x + threadIdx.x;
    int stride = gridDim.x * blockDim.x;
    for (; i < E4; i += stride) {
        int4 d = dst4[i];
        int4 s;
        s.x = atomicAdd(&ncnt[d.x], 1);
        s.y = atomicAdd(&ncnt[d.y], 1);
        s.z = atomicAdd(&ncnt[d.z], 1);
        s.w = atomicAdd(&ncnt[d.w], 1);
        slot4[i] = s;
    }
}

// ---- K2a: per-chunk sums of padded counts ----
__global__ void __launch_bounds__(SCAN_T) k_scan_part(
    const int* __restrict__ ncnt, int* __restrict__ bsum, int N) {
    __shared__ int red[SCAN_T];
    const int chunk = (N + SCAN_BLOCKS - 1) / SCAN_BLOCKS;
    const int beg = blockIdx.x * chunk;
    const int end = min(beg + chunk, N);
    int s = 0;
    for (int i = beg + threadIdx.x; i < end; i += SCAN_T) s += pad4(ncnt[i]);
    red[threadIdx.x] = s;
    __syncthreads();
    for (int d = SCAN_T / 2; d; d >>= 1) {
        if (threadIdx.x < d) red[threadIdx.x] += red[threadIdx.x + d];
        __syncthreads();
    }
    if (threadIdx.x == 0) bsum[blockIdx.x] = red[0];
}

// ---- K2b: exclusive scan of chunk sums (1 block) ----
__global__ void __launch_bounds__(SCAN_BLOCKS) k_scan_base(
    const int* __restrict__ bsum, int* __restrict__ bbase) {
    __shared__ int t[SCAN_BLOCKS];
    int tid = threadIdx.x;
    int v = bsum[tid];
    t[tid] = v;
    __syncthreads();
    for (int d = 1; d < SCAN_BLOCKS; d <<= 1) {
        int u = (tid >= d) ? t[tid - d] : 0;
        __syncthreads();
        t[tid] += u;
        __syncthreads();
    }
    bbase[tid] = t[tid] - v;
}

// ---- K2c: per-chunk exclusive scan -> off[] ----
__global__ void __launch_bounds__(SCAN_T) k_scan_chunk(
    const int* __restrict__ ncnt, const int* __restrict__ bbase,
    int* __restrict__ off, int N) {
    __shared__ int tmp[SCAN_T];
    const int chunk = (N + SCAN_BLOCKS - 1) / SCAN_BLOCKS;
    const int beg = blockIdx.x * chunk;
    const int end = min(beg + chunk, N);
    int base = bbase[blockIdx.x];
    for (int t0 = beg; t0 < end; t0 += SCAN_T) {
        int i = t0 + threadIdx.x;
        int v = (i < end) ? pad4(ncnt[i]) : 0;
        tmp[threadIdx.x] = v;
        __syncthreads();
        for (int d = 1; d < SCAN_T; d <<= 1) {
            int u = (threadIdx.x >= d) ? tmp[threadIdx.x - d] : 0;
            __syncthreads();
            tmp[threadIdx.x] += u;
            __syncthreads();
        }
        if (i < end) off[i] = base + tmp[threadIdx.x] - v;
        base += tmp[SCAN_T - 1];
        __syncthreads();
    }
    if (blockIdx.x == SCAN_BLOCKS - 1 && threadIdx.x == 0) off[N] = base;
}

// ---- K3: dinv ----
__global__ void __launch_bounds__(256) k_dinv(const int* __restrict__ ncnt,
                                              float* __restrict__ dinv, int N) {
    int i = blockIdx.x * blockDim.x + threadIdx.x;
    if (i < N) dinv[i] = rsqrtf((float)(ncnt[i] + 1));
}

// ---- K4: node GEMMs -> xg (half2{x, dinv*h_gcn}), hg (half h_gat), alphas ----
__global__ void __launch_bounds__(256) k_node_gemm(
    const float* __restrict__ x, const float* __restrict__ Wg,
    const float* __restrict__ Wa, const float* __restrict__ a_src,
    const float* __restrict__ a_dst, const float* __restrict__ dinv,
    unsigned int* __restrict__ xg, __half* __restrict__ hg,
    float* __restrict__ alpha_s, float* __restrict__ alpha_d, int N) {
    __shared__ float sWg[64 * 64];
    __shared__ float sWa[64 * 64];
    __shared__ float sas[64], sad[64];
    __shared__ float sx[4][64];

    for (int i = threadIdx.x; i < 64 * 64; i += 256) {
        sWg[i] = Wg[i];
        sWa[i] = Wa[i];
    }
    if (threadIdx.x < 64) {
        sas[threadIdx.x] = a_src[threadIdx.x];
        sad[threadIdx.x] = a_dst[threadIdx.x];
    }
    __syncthreads();

    // dummy node N: zero features, alpha_s = -1e30 (=> ee == 0)
    if (blockIdx.x == 0) {
        if (threadIdx.x < 64) {
            xg[(size_t)N * 64 + threadIdx.x] = 0u;
            hg[(size_t)N * 64 + threadIdx.x] = __float2half(0.f);
        }
        if (threadIdx.x == 64) alpha_s[N] = -1e30f;
    }

    const int lane = threadIdx.x & 63;
    const int rloc = threadIdx.x >> 6;

    for (int row0 = blockIdx.x * 4; row0 < N; row0 += gridDim.x * 4) {
        int row = row0 + rloc;
        if (row >= N) continue;
        float xv = x[(size_t)row * DIM + lane];
        sx[rloc][lane] = xv;  // same-wave LDS, wave-synchronous
        float accg = 0.f, acca = 0.f;
#pragma unroll
        for (int k = 0; k < 64; k++) {
            float xk = sx[rloc][k];
            accg = fmaf(xk, sWg[k * 64 + lane], accg);
            acca = fmaf(xk, sWa[k * 64 + lane], acca);
        }
        float g = dinv[row] * accg;
        __half2 pk = __floats2half2_rn(xv, g);
        xg[(size_t)row * 64 + lane] = *(unsigned int*)&pk;
        hg[(size_t)row * 64 + lane] = __float2half(acca);

        float ps = acca * sas[lane];
        float pd = acca * sad[lane];
#pragma unroll
        for (int offs = 32; offs; offs >>= 1) {
            ps += __shfl_xor(ps, offs, 64);
            pd += __shfl_xor(pd, offs, 64);
        }
        if (lane == 0) {
            alpha_s[row] = ps;
            alpha_d[row] = pd;
        }
    }
}

// ---- K5: fill pad slots with dummy node ----
__global__ void __launch_bounds__(256) k_pad(const int* __restrict__ ncnt,
                                             const int* __restrict__ off,
                                             int* __restrict__ srt, int N) {
    int i = blockIdx.x * blockDim.x + threadIdx.x;
    if (i >= N) return;
    int o = off[i] + ncnt[i];
    int p = off[i + 1];
    for (; o < p; o++) srt[o] = N_NODES;
}

// ---- K6: scatter src into CSR order (no atomics) ----
__global__ void __launch_bounds__(256) k_scatter(
    const int4* __restrict__ src4, const int4* __restrict__ dst4,
    const int4* __restrict__ slot4, const int* __restrict__ off,
    int* __restrict__ srt, int E4) {
    int i = blockIdx.x * blockDim.x + threadIdx.x;
    int stride = gridDim.x * blockDim.x;
    for (; i < E4; i += stride) {
        int4 s = src4[i];
        int4 d = dst4[i];
        int4 sl = slot4[i];
        srt[off[d.x] + sl.x] = s.x;
        srt[off[d.y] + sl.y] = s.y;
        srt[off[d.z] + sl.z] = s.z;
        srt[off[d.w] + sl.w] = s.w;
    }
}

// ---- K7: gather + full finalize. wave per node, lane = feature ----
__global__ void __launch_bounds__(1024) k_gather(
    const unsigned int* __restrict__ xg, const __half* __restrict__ hg,
    const float* __restrict__ alpha_s, const float* __restrict__ alpha_d,
    const float* __restrict__ dinv, const int* __restrict__ ncnt,
    const int* __restrict__ off, const int* __restrict__ srt,
    const float* __restrict__ Wss, const float* __restrict__ Wsn,
    const float* __restrict__ Wgin, const float* __restrict__ wts,
    float* __restrict__ out, int N) {
    __shared__ float sWss[64 * 64];
    __shared__ float sWsn[64 * 64];
    __shared__ float sWgin[64 * 64];
    __shared__ float sxn[16][2][64];

    for (int i = threadIdx.x; i < 64 * 64; i += 1024) {
        sWss[i] = Wss[i];
        sWsn[i] = Wsn[i];
        sWgin[i] = Wgin[i];
    }
    __syncthreads();

    const int lane = threadIdx.x & 63;
    const int w = threadIdx.x >> 6;
    const int wid = blockIdx.x * 16 + w;
    const int nw = gridDim.x * 16;
    const float w0 = wts[0], w1 = wts[1], w2 = wts[2], w3 = wts[3];

    for (int n = wid; n < N; n += nw) {
        const int off0 = off[n];
        const int pdeg = off[n + 1] - off0;  // multiple of 4
        const int deg = ncnt[n];
        const float as_d = alpha_s[n];
        const float ad_d = alpha_d[n];
        const float dv_d = dinv[n];

        float acc_n = 0.f, acc_g = 0.f, acc_gat = 0.f, den = 0.f;

        for (int c0 = 0; c0 < pdeg; c0 += 64) {
            int idx = c0 + lane;
            int sl = N_NODES;
            float ee_l = 0.f;
            if (idx < pdeg) {
                sl = srt[off0 + idx];
                ee_l = __expf(leaky_f(alpha_s[sl] + ad_d));
            }
            int jmax = min(64, pdeg - c0);  // multiple of 4
            for (int j = 0; j < jmax; j += 4) {
                int s0 = __shfl(sl, j, 64);
                int s1 = __shfl(sl, j + 1, 64);
                int s2 = __shfl(sl, j + 2, 64);
                int s3 = __shfl(sl, j + 3, 64);
                float e0 = __shfl(ee_l, j, 64);
                float e1 = __shfl(ee_l, j + 1, 64);
                float e2 = __shfl(ee_l, j + 2, 64);
                float e3 = __shfl(ee_l, j + 3, 64);
                unsigned int a0 = xg[(size_t)s0 * 64 + lane];
                unsigned int a1 = xg[(size_t)s1 * 64 + lane];
                unsigned int a2 = xg[(size_t)s2 * 64 + lane];
                unsigned int a3 = xg[(size_t)s3 * 64 + lane];
                __half h0 = hg[(size_t)s0 * 64 + lane];
                __half h1 = hg[(size_t)s1 * 64 + lane];
                __half h2 = hg[(size_t)s2 * 64 + lane];
                __half h3 = hg[(size_t)s3 * 64 + lane];
                float2 f0 = __half22float2(*(__half2*)&a0);
                float2 f1 = __half22float2(*(__half2*)&a1);
                float2 f2 = __half22float2(*(__half2*)&a2);
                float2 f3 = __half22float2(*(__half2*)&a3);
                acc_n += (f0.x + f1.x) + (f2.x + f3.x);
                acc_g += (f0.y + f1.y) + (f2.y + f3.y);
                acc_gat = fmaf(e0, __half2float(h0), acc_gat);
                acc_gat = fmaf(e1, __half2float(h1), acc_gat);
                acc_gat = fmaf(e2, __half2float(h2), acc_gat);
                acc_gat = fmaf(e3, __half2float(h3), acc_gat);
                den += (e0 + e1) + (e2 + e3);
            }
        }

        // self terms
        unsigned int aself = xg[(size_t)n * 64 + lane];
        __half hself = hg[(size_t)n * 64 + lane];
        float2 fs = __half22float2(*(__half2*)&aself);
        float xv = fs.x;
        float ee_s = __expf(leaky_f(as_d + ad_d));
        float gcn = dv_d * (acc_g + fs.y);
        float gat =
            (acc_gat + ee_s * __half2float(hself)) / (den + ee_s);

        // SAGE / GIN GEMMs
        sxn[w][0][lane] = xv;
        sxn[w][1][lane] = acc_n;
        float icnt = 1.f / fmaxf((float)deg, 1.f);
        float sage = 0.f, gin = 0.f;
#pragma unroll
        for (int k = 0; k < 64; k++) {
            float xk = sxn[w][0][k];
            float nk = sxn[w][1][k];
            sage = fmaf(xk, sWss[k * 64 + lane], sage);
            sage = fmaf(nk * icnt, sWsn[k * 64 + lane], sage);
            gin = fmaf(xk + nk, sWgin[k * 64 + lane], gin);
        }

        out[(size_t)n * DIM + lane] = w0 * elu_f(gcn) + w1 * elu_f(sage) +
                                      w2 * elu_f(gin) + w3 * elu_f(gat);
    }
}

extern "C" void kernel_launch(void* const* d_in, const int* in_sizes, int n_in,
                              void* d_out, int out_size, void* d_ws,
                              size_t ws_size, hipStream_t stream) {
    const float* x = (const float*)d_in[0];
    const float* wts = (const float*)d_in[1];
    const int* ei = (const int*)d_in[2];  // int32 (jax x64 disabled)
    const int* src = ei;
    const int* dst = ei + N_EDGES;
    const float* Wgcn = (const float*)d_in[3];
    const float* Wss = (const float*)d_in[4];
    const float* Wsn = (const float*)d_in[5];
    const float* Wgin = (const float*)d_in[6];
    const float* Wgat = (const float*)d_in[7];
    const float* a_src = (const float*)d_in[8];
    const float* a_dst = (const float*)d_in[9];
    float* out = (float*)d_out;

    const size_t N = N_NODES;
    const size_t E = N_EDGES;
    char* p = (char*)d_ws;
    unsigned int* xg = (unsigned int*)p;      // [(N+1)*64]
    p += (N + 1) * 64 * sizeof(unsigned int);
    __half* hg = (__half*)p;                  // [(N+1)*64]
    p += (N + 1) * 64 * sizeof(__half);
    int* slot = (int*)p;                      // [E]
    p += E * sizeof(int);
    int* srt = (int*)p;                       // [E + 3N + 16]
    p += (E + 3 * N + 16) * sizeof(int);
    float* alpha_s = (float*)p;               // [N+1]
    p += (N + 1) * sizeof(float);
    float* alpha_d = (float*)p;               // [N]
    p += N * sizeof(float);
    float* dinv = (float*)p;                  // [N]
    p += N * sizeof(float);
    int* ncnt = (int*)p;                      // [N] (zeroed)
    p += N * sizeof(int);
    int* off = (int*)p;                       // [N+1]
    p += (N + 1) * sizeof(int);
    int* bsum = (int*)p;                      // [SCAN_BLOCKS]
    p += SCAN_BLOCKS * sizeof(int);
    int* bbase = (int*)p;                     // [SCAN_BLOCKS]

    const int E4 = N_EDGES / 4;

    hipMemsetAsync(ncnt, 0, N * sizeof(int), stream);

    k_degree<<<(E4 + 255) / 256, 256, 0, stream>>>((const int4*)dst, ncnt,
                                                   (int4*)slot, E4);
    k_dinv<<<(N_NODES + 255) / 256, 256, 0, stream>>>(ncnt, dinv, N_NODES);
    k_node_gemm<<<2048, 256, 0, stream>>>(x, Wgcn, Wgat, a_src, a_dst, dinv,
                                          xg, hg, alpha_s, alpha_d, N_NODES);
    k_scan_part<<<SCAN_BLOCKS, SCAN_T, 0, stream>>>(ncnt, bsum, N_NODES);
    k_scan_base<<<1, SCAN_BLOCKS, 0, stream>>>(bsum, bbase);
    k_scan_chunk<<<SCAN_BLOCKS, SCAN_T, 0, stream>>>(ncnt, bbase, off,
                                                     N_NODES);
    k_pad<<<(N_NODES + 255) / 256, 256, 0, stream>>>(ncnt, off, srt, N_NODES);
    k_scatter<<<(E4 + 255) / 256, 256, 0, stream>>>(
        (const int4*)src, (const int4*)dst, (const int4*)slot, off, srt, E4);
    k_gather<<<512, 1024, 0, stream>>>(xg, hg, alpha_s, alpha_d, dinv, ncnt,
                                       off, srt, Wss, Wsn, Wgin, wts, out,
                                       N_NODES);
}

// Round 5
// 315.278 us; speedup vs baseline: 4.2262x; 1.6949x over previous
//
#include <hip/hip_runtime.h>
#include <hip/hip_fp16.h>

#define N_NODES 100000
#define N_EDGES 1600000
#define DIM 64
#define NEG_SLOPE 0.2f
#define SCAN_BLOCKS 128
#define SCAN_T 256

__device__ __forceinline__ float elu_f(float v) {
    return v > 0.f ? v : (__expf(v) - 1.f);
}
__device__ __forceinline__ float leaky_f(float v) {
    return v > 0.f ? v : NEG_SLOPE * v;
}
__device__ __forceinline__ int pad4(int v) { return (v + 3) & ~3; }

__device__ __forceinline__ unsigned int pkh2(float a, float b) {
    __half2 h = __floats2half2_rn(a, b);
    return *(unsigned int*)&h;
}
__device__ __forceinline__ float2 uph2(unsigned int u) {
    __half2 h = *(__half2*)&u;
    return __half22float2(h);
}

typedef _Float16 half2_raw __attribute__((ext_vector_type(2)));
__device__ __forceinline__ float fdot2u(unsigned int a, unsigned int b,
                                        float c) {
#if __has_builtin(__builtin_amdgcn_fdot2)
    half2_raw ha, hb;
    __builtin_memcpy(&ha, &a, 4);
    __builtin_memcpy(&hb, &b, 4);
    return __builtin_amdgcn_fdot2(ha, hb, c, false);
#else
    float2 f1 = uph2(a), f2 = uph2(b);
    return fmaf(f1.x, f2.x, fmaf(f1.y, f2.y, c));
#endif
}

// ---- K0: v_src = Wgat @ a_src, v_dst = Wgat @ a_dst; dummy-node init ----
__global__ void __launch_bounds__(128) k_prep(const float* __restrict__ Wgat,
                                              const float* __restrict__ a_src,
                                              const float* __restrict__ a_dst,
                                              float* __restrict__ vsd,
                                              unsigned int* __restrict__ xh,
                                              float2* __restrict__ scal2) {
    int t = threadIdx.x;
    if (t < 64) {
        float vs = 0.f, vd = 0.f;
        for (int j = 0; j < 64; j++) {
            float w = Wgat[t * 64 + j];
            vs = fmaf(w, a_src[j], vs);
            vd = fmaf(w, a_dst[j], vd);
        }
        vsd[t] = vs;
        vsd[64 + t] = vd;
    } else if (t < 96) {
        xh[(size_t)N_NODES * 32 + (t - 64)] = 0u;  // dummy node row = 0
    } else if (t == 96) {
        scal2[N_NODES] = make_float2(-1e30f, 0.f);  // ee=0, dinv=0
    }
}

// ---- K1: pack x -> half2, alphas via dot with v_src/v_dst ----
__global__ void __launch_bounds__(256) k_pack(const float2* __restrict__ xf2,
                                              const float* __restrict__ vsd,
                                              unsigned int* __restrict__ xh,
                                              float2* __restrict__ scal2,
                                              float* __restrict__ alpha_d,
                                              int N) {
    __shared__ float svs[64], svd[64];
    if (threadIdx.x < 64) svs[threadIdx.x] = vsd[threadIdx.x];
    else if (threadIdx.x < 128) svd[threadIdx.x - 64] = vsd[threadIdx.x];
    __syncthreads();

    const int lane = threadIdx.x & 63;
    const int wv = threadIdx.x >> 6;
    const int c = lane & 31;
    const int g = lane >> 5;
    const int npairs = N / 2;

    for (int pr = blockIdx.x * 4 + wv; pr < npairs; pr += gridDim.x * 4) {
        int n = pr * 2 + g;
        float2 x2 = xf2[(size_t)n * 32 + c];
        xh[(size_t)n * 32 + c] = pkh2(x2.x, x2.y);
        float ps = x2.x * svs[2 * c] + x2.y * svs[2 * c + 1];
        float pd = x2.x * svd[2 * c] + x2.y * svd[2 * c + 1];
#pragma unroll
        for (int m = 16; m; m >>= 1) {
            ps += __shfl_xor(ps, m, 32);
            pd += __shfl_xor(pd, m, 32);
        }
        if (c == 0) {
            scal2[n].x = ps;
            alpha_d[n] = pd;
        }
    }
}

// ---- K2: degree count + per-edge slot (int4 vectorized) ----
__global__ void __launch_bounds__(256) k_degree(const int4* __restrict__ dst4,
                                                int* __restrict__ ncnt,
                                                int4* __restrict__ slot4,
                                                int E4) {
    int i = blockIdx.x * blockDim.x + threadIdx.x;
    int stride = gridDim.x * blockDim.x;
    for (; i < E4; i += stride) {
        int4 d = dst4[i];
        int4 s;
        s.x = atomicAdd(&ncnt[d.x], 1);
        s.y = atomicAdd(&ncnt[d.y], 1);
        s.z = atomicAdd(&ncnt[d.z], 1);
        s.w = atomicAdd(&ncnt[d.w], 1);
        slot4[i] = s;
    }
}

// ---- K3a: per-chunk sums of padded counts ----
__global__ void __launch_bounds__(SCAN_T) k_scan_part(
    const int* __restrict__ ncnt, int* __restrict__ bsum, int N) {
    __shared__ int red[SCAN_T];
    const int chunk = (N + SCAN_BLOCKS - 1) / SCAN_BLOCKS;
    const int beg = blockIdx.x * chunk;
    const int end = min(beg + chunk, N);
    int s = 0;
    for (int i = beg + threadIdx.x; i < end; i += SCAN_T) s += pad4(ncnt[i]);
    red[threadIdx.x] = s;
    __syncthreads();
    for (int d = SCAN_T / 2; d; d >>= 1) {
        if (threadIdx.x < d) red[threadIdx.x] += red[threadIdx.x + d];
        __syncthreads();
    }
    if (threadIdx.x == 0) bsum[blockIdx.x] = red[0];
}

// ---- K3b: exclusive scan of chunk sums ----
__global__ void __launch_bounds__(SCAN_BLOCKS) k_scan_base(
    const int* __restrict__ bsum, int* __restrict__ bbase) {
    __shared__ int t[SCAN_BLOCKS];
    int tid = threadIdx.x;
    int v = bsum[tid];
    t[tid] = v;
    __syncthreads();
    for (int d = 1; d < SCAN_BLOCKS; d <<= 1) {
        int u = (tid >= d) ? t[tid - d] : 0;
        __syncthreads();
        t[tid] += u;
        __syncthreads();
    }
    bbase[tid] = t[tid] - v;
}

// ---- K3c: per-chunk exclusive scan -> off[]; + dinv; + pad fill ----
__global__ void __launch_bounds__(SCAN_T) k_scan_chunk(
    const int* __restrict__ ncnt, const int* __restrict__ bbase,
    int* __restrict__ off, float2* __restrict__ scal2, int* __restrict__ srt,
    int N) {
    __shared__ int tmp[SCAN_T];
    const int chunk = (N + SCAN_BLOCKS - 1) / SCAN_BLOCKS;
    const int beg = blockIdx.x * chunk;
    const int end = min(beg + chunk, N);
    int base = bbase[blockIdx.x];
    for (int t0 = beg; t0 < end; t0 += SCAN_T) {
        int i = t0 + threadIdx.x;
        int cnt = (i < end) ? ncnt[i] : 0;
        int v = pad4(cnt);
        tmp[threadIdx.x] = v;
        __syncthreads();
        for (int d = 1; d < SCAN_T; d <<= 1) {
            int u = (threadIdx.x >= d) ? tmp[threadIdx.x - d] : 0;
            __syncthreads();
            tmp[threadIdx.x] += u;
            __syncthreads();
        }
        if (i < end) {
            int pos = base + tmp[threadIdx.x] - v;
            off[i] = pos;
            scal2[i].y = rsqrtf((float)(cnt + 1));
            for (int t = cnt; t < v; t++) srt[pos + t] = N_NODES;
        }
        base += tmp[SCAN_T - 1];
        __syncthreads();
    }
    if (blockIdx.x == SCAN_BLOCKS - 1 && threadIdx.x == 0) off[N] = base;
}

// ---- K4: scatter src into CSR order (no atomics) ----
__global__ void __launch_bounds__(256) k_scatter(
    const int4* __restrict__ src4, const int4* __restrict__ dst4,
    const int4* __restrict__ slot4, const int* __restrict__ off,
    int* __restrict__ srt, int E4) {
    int i = blockIdx.x * blockDim.x + threadIdx.x;
    int stride = gridDim.x * blockDim.x;
    for (; i < E4; i += stride) {
        int4 s = src4[i];
        int4 d = dst4[i];
        int4 sl = slot4[i];
        srt[off[d.x] + sl.x] = s.x;
        srt[off[d.y] + sl.y] = s.y;
        srt[off[d.z] + sl.z] = s.z;
        srt[off[d.w] + sl.w] = s.w;
    }
}

// ---- K5: gather x-only + fused 5-matvec finalize. wave per node ----
__global__ void __launch_bounds__(1024) k_gather(
    const unsigned int* __restrict__ xh, const float2* __restrict__ xf2,
    const float2* __restrict__ scal2, const float* __restrict__ alpha_d,
    const int* __restrict__ ncnt, const int* __restrict__ off,
    const int* __restrict__ srt, const float* __restrict__ Wgcn,
    const float* __restrict__ Wss, const float* __restrict__ Wsn,
    const float* __restrict__ Wgin, const float* __restrict__ Wgat,
    const float* __restrict__ wts, float* __restrict__ out, int N) {
    __shared__ unsigned int sW[5][2048];  // half2-packed [kk*64+o], 40KB
    __shared__ uint4 sv4[16][32][2];      // 5 half2 vectors per wave, 16KB
    __shared__ int sSl[16][64];           // 4KB
    __shared__ float2 sED[16][64];        // 8KB

#pragma unroll
    for (int m = 0; m < 5; m++) {
        const float* Wm = (m == 0)   ? Wgcn
                          : (m == 1) ? Wss
                          : (m == 2) ? Wsn
                          : (m == 3) ? Wgin
                                     : Wgat;
        for (int idx = threadIdx.x; idx < 2048; idx += 1024) {
            int kk = idx >> 6, o = idx & 63;
            sW[m][idx] = pkh2(Wm[(2 * kk) * 64 + o], Wm[(2 * kk + 1) * 64 + o]);
        }
    }
    __syncthreads();

    const int lane = threadIdx.x & 63;
    const int w = threadIdx.x >> 6;
    const int c = lane & 31;
    const int hf = lane >> 5;
    const int wid = blockIdx.x * 16 + w;
    const int nw = gridDim.x * 16;
    const float w0 = wts[0], w1 = wts[1], w2 = wts[2], w3 = wts[3];

    for (int n = wid; n < N; n += nw) {
        const int off0 = off[n];
        const int pdeg = off[n + 1] - off0;  // multiple of 4
        const float2 sc_d = scal2[n];
        const float as_d = sc_d.x;
        const float dv_d = sc_d.y;
        const float ad_d = alpha_d[n];

        float2 an = {0.f, 0.f}, ag = {0.f, 0.f}, aa = {0.f, 0.f};
        float den = 0.f;

        for (int c0 = 0; c0 < pdeg; c0 += 64) {
            int idx = c0 + lane;
            int sl = (idx < pdeg) ? srt[off0 + idx] : N_NODES;
            float2 sc = scal2[sl];
            float ee = __expf(leaky_f(sc.x + ad_d));
            den += ee;
            sSl[w][lane] = sl;
            sED[w][lane] = make_float2(ee, sc.y);
            int jmax = min(64, pdeg - c0);  // multiple of 4
            for (int j = 0; j < jmax; j += 4) {
                int b0 = j + hf;
                int b1 = b0 + 2;
                int s0 = sSl[w][b0];
                int s1 = sSl[w][b1];
                float2 e0 = sED[w][b0];
                float2 e1 = sED[w][b1];
                unsigned int u0 = xh[(size_t)s0 * 32 + c];
                unsigned int u1 = xh[(size_t)s1 * 32 + c];
                float2 f0 = uph2(u0);
                float2 f1 = uph2(u1);
                an.x += f0.x + f1.x;
                an.y += f0.y + f1.y;
                ag.x = fmaf(e0.y, f0.x, fmaf(e1.y, f1.x, ag.x));
                ag.y = fmaf(e0.y, f0.y, fmaf(e1.y, f1.y, ag.y));
                aa.x = fmaf(e0.x, f0.x, fmaf(e1.x, f1.x, aa.x));
                aa.y = fmaf(e0.x, f0.y, fmaf(e1.x, f1.y, aa.y));
            }
        }

        // reduce den across wave; combine half-wave feature accumulators
#pragma unroll
        for (int m = 32; m; m >>= 1) den += __shfl_xor(den, m, 64);
        const int prt = c + 32;
        an.x += __shfl(an.x, prt, 64);
        an.y += __shfl(an.y, prt, 64);
        ag.x += __shfl(ag.x, prt, 64);
        ag.y += __shfl(ag.y, prt, 64);
        aa.x += __shfl(aa.x, prt, 64);
        aa.y += __shfl(aa.y, prt, 64);

        if (lane < 32) {
            float2 xd = xf2[(size_t)n * 32 + c];
            float ee_s = __expf(leaky_f(as_d + ad_d));
            float dent = den + ee_s;
            float deg = (float)ncnt[n];
            float icnt = 1.f / fmaxf(deg, 1.f);
            float dv2 = dv_d * dv_d;
            uint4 q;
            q.x = pkh2(fmaf(dv_d, ag.x, dv2 * xd.x),
                       fmaf(dv_d, ag.y, dv2 * xd.y));        // GCN vec
            q.y = pkh2(xd.x, xd.y);                          // x (Wss)
            q.z = pkh2(an.x * icnt, an.y * icnt);            // nmean (Wsn)
            q.w = pkh2(xd.x + an.x, xd.y + an.y);            // GIN vec
            sv4[w][c][0] = q;
            uint4 q2;
            q2.x = pkh2(fmaf(ee_s, xd.x, aa.x) / dent,
                        fmaf(ee_s, xd.y, aa.y) / dent);      // GAT vec
            q2.y = q2.z = q2.w = 0u;
            sv4[w][c][1] = q2;
        }

        float a0 = 0.f, a1 = 0.f, a2 = 0.f, a3 = 0.f, a4 = 0.f;
#pragma unroll
        for (int kk = 0; kk < 32; kk++) {
            uint4 q = sv4[w][kk][0];
            unsigned int q4 = sv4[w][kk][1].x;
            const int base = kk * 64 + lane;
            a0 = fdot2u(q.x, sW[0][base], a0);
            a1 = fdot2u(q.y, sW[1][base], a1);
            a2 = fdot2u(q.z, sW[2][base], a2);
            a3 = fdot2u(q.w, sW[3][base], a3);
            a4 = fdot2u(q4, sW[4][base], a4);
        }

        out[(size_t)n * DIM + lane] = w0 * elu_f(a0) + w1 * elu_f(a1 + a2) +
                                      w2 * elu_f(a3) + w3 * elu_f(a4);
    }
}

extern "C" void kernel_launch(void* const* d_in, const int* in_sizes, int n_in,
                              void* d_out, int out_size, void* d_ws,
                              size_t ws_size, hipStream_t stream) {
    const float* x = (const float*)d_in[0];
    const float* wts = (const float*)d_in[1];
    const int* ei = (const int*)d_in[2];  // int32 (jax x64 disabled)
    const int* src = ei;
    const int* dst = ei + N_EDGES;
    const float* Wgcn = (const float*)d_in[3];
    const float* Wss = (const float*)d_in[4];
    const float* Wsn = (const float*)d_in[5];
    const float* Wgin = (const float*)d_in[6];
    const float* Wgat = (const float*)d_in[7];
    const float* a_src = (const float*)d_in[8];
    const float* a_dst = (const float*)d_in[9];
    float* out = (float*)d_out;

    const size_t N = N_NODES;
    const size_t E = N_EDGES;
    char* p = (char*)d_ws;
    unsigned int* xh = (unsigned int*)p;  // [(N+1)*32]
    p += (N + 1) * 32 * sizeof(unsigned int);
    int* slot = (int*)p;  // [E]
    p += E * sizeof(int);
    int* srt = (int*)p;  // [E + 3N + 64]
    p += (E + 3 * N + 64) * sizeof(int);
    float2* scal2 = (float2*)p;  // [N+1] {alpha_s, dinv}
    p += (N + 1) * sizeof(float2);
    float* alpha_d = (float*)p;  // [N]
    p += N * sizeof(float);
    int* ncnt = (int*)p;  // [N] (zeroed)
    p += N * sizeof(int);
    int* off = (int*)p;  // [N+1]
    p += (N + 1) * sizeof(int);
    int* bsum = (int*)p;  // [SCAN_BLOCKS]
    p += SCAN_BLOCKS * sizeof(int);
    int* bbase = (int*)p;  // [SCAN_BLOCKS]
    p += SCAN_BLOCKS * sizeof(int);
    float* vsd = (float*)p;  // [128] v_src|v_dst

    const int E4 = N_EDGES / 4;

    hipMemsetAsync(ncnt, 0, N * sizeof(int), stream);

    k_prep<<<1, 128, 0, stream>>>(Wgat, a_src, a_dst, vsd, xh, scal2);
    k_pack<<<1024, 256, 0, stream>>>((const float2*)x, vsd, xh, scal2,
                                     alpha_d, N_NODES);
    k_degree<<<(E4 + 255) / 256, 256, 0, stream>>>((const int4*)dst, ncnt,
                                                   (int4*)slot, E4);
    k_scan_part<<<SCAN_BLOCKS, SCAN_T, 0, stream>>>(ncnt, bsum, N_NODES);
    k_scan_base<<<1, SCAN_BLOCKS, 0, stream>>>(bsum, bbase);
    k_scan_chunk<<<SCAN_BLOCKS, SCAN_T, 0, stream>>>(ncnt, bbase, off, scal2,
                                                     srt, N_NODES);
    k_scatter<<<(E4 + 255) / 256, 256, 0, stream>>>(
        (const int4*)src, (const int4*)dst, (const int4*)slot, off, srt, E4);
    k_gather<<<512, 1024, 0, stream>>>(xh, (const float2*)x, scal2, alpha_d,
                                       ncnt, off, srt, Wgcn, Wss, Wsn, Wgin,
                                       Wgat, wts, out, N_NODES);
}

// Round 6
// 292.642 us; speedup vs baseline: 4.5531x; 1.0774x over previous
//
#include <hip/hip_runtime.h>
#include <hip/hip_fp16.h>

#define N_NODES 100000
#define N_EDGES 1600000
#define DIM 64
#define NEG_SLOPE 0.2f
#define SCAN_BLOCKS 128
#define SCAN_T 256

__device__ __forceinline__ float elu_f(float v) {
    return v > 0.f ? v : (__expf(v) - 1.f);
}
__device__ __forceinline__ float leaky_f(float v) {
    return v > 0.f ? v : NEG_SLOPE * v;
}
__device__ __forceinline__ int pad4(int v) { return (v + 3) & ~3; }

__device__ __forceinline__ unsigned int pkh2(float a, float b) {
    __half2 h = __floats2half2_rn(a, b);
    return *(unsigned int*)&h;
}
__device__ __forceinline__ float2 uph2(unsigned int u) {
    __half2 h = *(__half2*)&u;
    return __half22float2(h);
}

typedef _Float16 half2_raw __attribute__((ext_vector_type(2)));
__device__ __forceinline__ float fdot2u(unsigned int a, unsigned int b,
                                        float c) {
#if __has_builtin(__builtin_amdgcn_fdot2)
    half2_raw ha, hb;
    __builtin_memcpy(&ha, &a, 4);
    __builtin_memcpy(&hb, &b, 4);
    return __builtin_amdgcn_fdot2(ha, hb, c, false);
#else
    float2 f1 = uph2(a), f2 = uph2(b);
    return fmaf(f1.x, f2.x, fmaf(f1.y, f2.y, c));
#endif
}

// ---- K1: pack x -> half2; alphas via dot with v_src/v_dst (computed per block);
//          block 0 also inits the dummy node ----
__global__ void __launch_bounds__(256) k_pack(const float2* __restrict__ xf2,
                                              const float* __restrict__ Wgat,
                                              const float* __restrict__ a_src,
                                              const float* __restrict__ a_dst,
                                              unsigned int* __restrict__ xh,
                                              float2* __restrict__ scal2,
                                              float* __restrict__ alpha_d,
                                              int N) {
    __shared__ float svs[64], svd[64];
    if (threadIdx.x < 64) {
        int t = threadIdx.x;
        float vs = 0.f, vd = 0.f;
        for (int j = 0; j < 64; j++) {
            float w = Wgat[t * 64 + j];
            vs = fmaf(w, a_src[j], vs);
            vd = fmaf(w, a_dst[j], vd);
        }
        svs[t] = vs;
        svd[t] = vd;
    }
    __syncthreads();

    if (blockIdx.x == 0) {
        if (threadIdx.x < 32) xh[(size_t)N * 32 + threadIdx.x] = 0u;
        if (threadIdx.x == 32) scal2[N] = make_float2(-1e30f, 0.f);
    }

    const int lane = threadIdx.x & 63;
    const int wv = threadIdx.x >> 6;
    const int c = lane & 31;
    const int g = lane >> 5;
    const int npairs = N / 2;

    for (int pr = blockIdx.x * 4 + wv; pr < npairs; pr += gridDim.x * 4) {
        int n = pr * 2 + g;
        float2 x2 = xf2[(size_t)n * 32 + c];
        xh[(size_t)n * 32 + c] = pkh2(x2.x, x2.y);
        float ps = x2.x * svs[2 * c] + x2.y * svs[2 * c + 1];
        float pd = x2.x * svd[2 * c] + x2.y * svd[2 * c + 1];
#pragma unroll
        for (int m = 16; m; m >>= 1) {
            ps += __shfl_xor(ps, m, 32);
            pd += __shfl_xor(pd, m, 32);
        }
        if (c == 0) {
            scal2[n].x = ps;
            alpha_d[n] = pd;
        }
    }
}

// ---- K2: degree count + per-edge slot (int4 vectorized) ----
__global__ void __launch_bounds__(256) k_degree(const int4* __restrict__ dst4,
                                                int* __restrict__ ncnt,
                                                int4* __restrict__ slot4,
                                                int E4) {
    int i = blockIdx.x * blockDim.x + threadIdx.x;
    int stride = gridDim.x * blockDim.x;
    for (; i < E4; i += stride) {
        int4 d = dst4[i];
        int4 s;
        s.x = atomicAdd(&ncnt[d.x], 1);
        s.y = atomicAdd(&ncnt[d.y], 1);
        s.z = atomicAdd(&ncnt[d.z], 1);
        s.w = atomicAdd(&ncnt[d.w], 1);
        slot4[i] = s;
    }
}

// ---- K3a: per-chunk sums of padded counts ----
__global__ void __launch_bounds__(SCAN_T) k_scan_part(
    const int* __restrict__ ncnt, int* __restrict__ bsum, int N) {
    __shared__ int red[SCAN_T];
    const int chunk = (N + SCAN_BLOCKS - 1) / SCAN_BLOCKS;
    const int beg = blockIdx.x * chunk;
    const int end = min(beg + chunk, N);
    int s = 0;
    for (int i = beg + threadIdx.x; i < end; i += SCAN_T) s += pad4(ncnt[i]);
    red[threadIdx.x] = s;
    __syncthreads();
    for (int d = SCAN_T / 2; d; d >>= 1) {
        if (threadIdx.x < d) red[threadIdx.x] += red[threadIdx.x + d];
        __syncthreads();
    }
    if (threadIdx.x == 0) bsum[blockIdx.x] = red[0];
}

// ---- K3b: exclusive scan of chunk sums ----
__global__ void __launch_bounds__(SCAN_BLOCKS) k_scan_base(
    const int* __restrict__ bsum, int* __restrict__ bbase) {
    __shared__ int t[SCAN_BLOCKS];
    int tid = threadIdx.x;
    int v = bsum[tid];
    t[tid] = v;
    __syncthreads();
    for (int d = 1; d < SCAN_BLOCKS; d <<= 1) {
        int u = (tid >= d) ? t[tid - d] : 0;
        __syncthreads();
        t[tid] += u;
        __syncthreads();
    }
    bbase[tid] = t[tid] - v;
}

// ---- K3c: per-chunk exclusive scan -> off[] + node header + dinv + pad fill ----
__global__ void __launch_bounds__(SCAN_T) k_scan_chunk(
    const int* __restrict__ ncnt, const int* __restrict__ bbase,
    const float* __restrict__ alpha_d, int* __restrict__ off,
    float2* __restrict__ scal2, int4* __restrict__ hdr4, int* __restrict__ srt,
    int N) {
    __shared__ int tmp[SCAN_T];
    const int chunk = (N + SCAN_BLOCKS - 1) / SCAN_BLOCKS;
    const int beg = blockIdx.x * chunk;
    const int end = min(beg + chunk, N);
    int base = bbase[blockIdx.x];
    for (int t0 = beg; t0 < end; t0 += SCAN_T) {
        int i = t0 + threadIdx.x;
        int cnt = (i < end) ? ncnt[i] : 0;
        int v = pad4(cnt);
        tmp[threadIdx.x] = v;
        __syncthreads();
        for (int d = 1; d < SCAN_T; d <<= 1) {
            int u = (threadIdx.x >= d) ? tmp[threadIdx.x - d] : 0;
            __syncthreads();
            tmp[threadIdx.x] += u;
            __syncthreads();
        }
        if (i < end) {
            int pos = base + tmp[threadIdx.x] - v;
            off[i] = pos;
            float dv = rsqrtf((float)(cnt + 1));
            scal2[i].y = dv;
            hdr4[i] = make_int4(pos, cnt, __float_as_int(alpha_d[i]),
                                __float_as_int(dv));
            for (int t = cnt; t < v; t++) srt[pos + t] = N_NODES;
        }
        base += tmp[SCAN_T - 1];
        __syncthreads();
    }
}

// ---- K4: scatter src into CSR order (no atomics) ----
__global__ void __launch_bounds__(256) k_scatter(
    const int4* __restrict__ src4, const int4* __restrict__ dst4,
    const int4* __restrict__ slot4, const int* __restrict__ off,
    int* __restrict__ srt, int E4) {
    int i = blockIdx.x * blockDim.x + threadIdx.x;
    int stride = gridDim.x * blockDim.x;
    for (; i < E4; i += stride) {
        int4 s = src4[i];
        int4 d = dst4[i];
        int4 sl = slot4[i];
        srt[off[d.x] + sl.x] = s.x;
        srt[off[d.y] + sl.y] = s.y;
        srt[off[d.z] + sl.z] = s.z;
        srt[off[d.w] + sl.w] = s.w;
    }
}

// ---- K5: aggregation only. wave per node, 8 edges/iter, half2 features ----
__global__ void __launch_bounds__(1024) k_agg(
    const unsigned int* __restrict__ xh, const float2* __restrict__ scal2,
    const int4* __restrict__ hdr4, const int* __restrict__ srt,
    unsigned int* __restrict__ aggN, unsigned int* __restrict__ aggG,
    unsigned int* __restrict__ aggA, float* __restrict__ aggD, int N) {
    __shared__ int sSl[16][64];
    __shared__ float2 sED[16][64];

    const int lane = threadIdx.x & 63;
    const int w = threadIdx.x >> 6;
    const int c = lane & 31;
    const int hf = lane >> 5;
    const int wid = blockIdx.x * 16 + w;
    const int nw = gridDim.x * 16;

    for (int n = wid; n < N; n += nw) {
        const int4 h = hdr4[n];
        const int off0 = h.x;
        const int pdeg = pad4(h.y);
        const float ad = __int_as_float(h.z);

        float2 an = {0.f, 0.f}, ag = {0.f, 0.f}, aa = {0.f, 0.f};
        float den = 0.f;

        for (int c0 = 0; c0 < pdeg; c0 += 64) {
            int idx = c0 + lane;
            int sl = (idx < pdeg) ? srt[off0 + idx] : N_NODES;
            float2 sc = scal2[sl];
            float ee = __expf(leaky_f(sc.x + ad));
            den += ee;
            sSl[w][lane] = sl;
            sED[w][lane] = make_float2(ee, sc.y);
            int jmax = min(64, pdeg - c0);  // multiple of 4
            int j = 0;
            for (; j + 8 <= jmax; j += 8) {
                int b0 = j + hf, b1 = b0 + 2, b2 = b0 + 4, b3 = b0 + 6;
                int s0 = sSl[w][b0], s1 = sSl[w][b1];
                int s2 = sSl[w][b2], s3 = sSl[w][b3];
                float2 e0 = sED[w][b0], e1 = sED[w][b1];
                float2 e2 = sED[w][b2], e3 = sED[w][b3];
                unsigned int u0 = xh[(size_t)s0 * 32 + c];
                unsigned int u1 = xh[(size_t)s1 * 32 + c];
                unsigned int u2 = xh[(size_t)s2 * 32 + c];
                unsigned int u3 = xh[(size_t)s3 * 32 + c];
                float2 f0 = uph2(u0), f1 = uph2(u1);
                float2 f2 = uph2(u2), f3 = uph2(u3);
                an.x += (f0.x + f1.x) + (f2.x + f3.x);
                an.y += (f0.y + f1.y) + (f2.y + f3.y);
                ag.x = fmaf(e0.y, f0.x,
                            fmaf(e1.y, f1.x, fmaf(e2.y, f2.x,
                                                  fmaf(e3.y, f3.x, ag.x))));
                ag.y = fmaf(e0.y, f0.y,
                            fmaf(e1.y, f1.y, fmaf(e2.y, f2.y,
                                                  fmaf(e3.y, f3.y, ag.y))));
                aa.x = fmaf(e0.x, f0.x,
                            fmaf(e1.x, f1.x, fmaf(e2.x, f2.x,
                                                  fmaf(e3.x, f3.x, aa.x))));
                aa.y = fmaf(e0.x, f0.y,
                            fmaf(e1.x, f1.y, fmaf(e2.x, f2.y,
                                                  fmaf(e3.x, f3.y, aa.y))));
            }
            if (j < jmax) {  // 4-edge tail
                int b0 = j + hf, b1 = b0 + 2;
                int s0 = sSl[w][b0], s1 = sSl[w][b1];
                float2 e0 = sED[w][b0], e1 = sED[w][b1];
                unsigned int u0 = xh[(size_t)s0 * 32 + c];
                unsigned int u1 = xh[(size_t)s1 * 32 + c];
                float2 f0 = uph2(u0), f1 = uph2(u1);
                an.x += f0.x + f1.x;
                an.y += f0.y + f1.y;
                ag.x = fmaf(e0.y, f0.x, fmaf(e1.y, f1.x, ag.x));
                ag.y = fmaf(e0.y, f0.y, fmaf(e1.y, f1.y, ag.y));
                aa.x = fmaf(e0.x, f0.x, fmaf(e1.x, f1.x, aa.x));
                aa.y = fmaf(e0.x, f0.y, fmaf(e1.x, f1.y, aa.y));
            }
        }

        // combine the two half-waves (each covers all 64 features, different edges)
        an.x += __shfl_xor(an.x, 32, 64);
        an.y += __shfl_xor(an.y, 32, 64);
        ag.x += __shfl_xor(ag.x, 32, 64);
        ag.y += __shfl_xor(ag.y, 32, 64);
        aa.x += __shfl_xor(aa.x, 32, 64);
        aa.y += __shfl_xor(aa.y, 32, 64);
#pragma unroll
        for (int m = 32; m; m >>= 1) den += __shfl_xor(den, m, 64);

        if (lane < 32) {
            size_t o = (size_t)n * 32 + c;
            aggN[o] = pkh2(an.x, an.y);
            aggG[o] = pkh2(ag.x, ag.y);
            aggA[o] = pkh2(aa.x, aa.y);
        }
        if (lane == 0) aggD[n] = den;
    }
}

// ---- K6: dense finalize. wave per node, 5 matvecs via v_dot2 ----
__global__ void __launch_bounds__(512) k_finalize(
    const float2* __restrict__ xf2, const unsigned int* __restrict__ aggN,
    const unsigned int* __restrict__ aggG, const unsigned int* __restrict__ aggA,
    const float* __restrict__ aggD, const float2* __restrict__ scal2,
    const int4* __restrict__ hdr4, const float* __restrict__ Wgcn,
    const float* __restrict__ Wss, const float* __restrict__ Wsn,
    const float* __restrict__ Wgin, const float* __restrict__ Wgat,
    const float* __restrict__ wts, float* __restrict__ out, int N) {
    __shared__ unsigned int sW[5][2048];  // half2-packed, 40KB
    __shared__ uint4 sv4[8][32][2];       // 8KB

#pragma unroll
    for (int m = 0; m < 5; m++) {
        const float* Wm = (m == 0)   ? Wgcn
                          : (m == 1) ? Wss
                          : (m == 2) ? Wsn
                          : (m == 3) ? Wgin
                                     : Wgat;
        for (int idx = threadIdx.x; idx < 2048; idx += 512) {
            int kk = idx >> 6, o = idx & 63;
            sW[m][idx] = pkh2(Wm[(2 * kk) * 64 + o], Wm[(2 * kk + 1) * 64 + o]);
        }
    }
    __syncthreads();

    const int lane = threadIdx.x & 63;
    const int rloc = threadIdx.x >> 6;  // 0..7
    const int c = lane & 31;
    const float w0 = wts[0], w1 = wts[1], w2 = wts[2], w3 = wts[3];

    for (int row0 = blockIdx.x * 8; row0 < N; row0 += gridDim.x * 8) {
        int n = row0 + rloc;
        if (n >= N) continue;

        if (lane < 32) {
            size_t o = (size_t)n * 32 + c;
            float2 xd = xf2[o];
            float2 nn = uph2(aggN[o]);
            float2 gg = uph2(aggG[o]);
            float2 av = uph2(aggA[o]);
            float den = aggD[n];
            int4 h = hdr4[n];
            float ad = __int_as_float(h.z);
            float dv = __int_as_float(h.w);
            float as = scal2[n].x;
            float ee_s = __expf(leaky_f(as + ad));
            float dent = den + ee_s;
            float icnt = 1.f / fmaxf((float)h.y, 1.f);
            float dv2 = dv * dv;
            uint4 q;
            q.x = pkh2(fmaf(dv, gg.x, dv2 * xd.x),
                       fmaf(dv, gg.y, dv2 * xd.y));       // GCN vec
            q.y = pkh2(xd.x, xd.y);                       // x (Wss)
            q.z = pkh2(nn.x * icnt, nn.y * icnt);         // nmean (Wsn)
            q.w = pkh2(xd.x + nn.x, xd.y + nn.y);         // GIN vec
            sv4[rloc][c][0] = q;
            uint4 q2;
            q2.x = pkh2(fmaf(ee_s, xd.x, av.x) / dent,
                        fmaf(ee_s, xd.y, av.y) / dent);   // GAT vec
            q2.y = q2.z = q2.w = 0u;
            sv4[rloc][c][1] = q2;
        }
        // same-wave LDS write->read: wave-synchronous

        float a0 = 0.f, a1 = 0.f, a2 = 0.f, a3 = 0.f, a4 = 0.f;
#pragma unroll
        for (int kk = 0; kk < 32; kk++) {
            uint4 q = sv4[rloc][kk][0];
            unsigned int q4 = sv4[rloc][kk][1].x;
            const int base = kk * 64 + lane;
            a0 = fdot2u(q.x, sW[0][base], a0);
            a1 = fdot2u(q.y, sW[1][base], a1);
            a2 = fdot2u(q.z, sW[2][base], a2);
            a3 = fdot2u(q.w, sW[3][base], a3);
            a4 = fdot2u(q4, sW[4][base], a4);
        }

        out[(size_t)n * DIM + lane] = w0 * elu_f(a0) + w1 * elu_f(a1 + a2) +
                                      w2 * elu_f(a3) + w3 * elu_f(a4);
    }
}

extern "C" void kernel_launch(void* const* d_in, const int* in_sizes, int n_in,
                              void* d_out, int out_size, void* d_ws,
                              size_t ws_size, hipStream_t stream) {
    const float* x = (const float*)d_in[0];
    const float* wts = (const float*)d_in[1];
    const int* ei = (const int*)d_in[2];  // int32 (jax x64 disabled)
    const int* src = ei;
    const int* dst = ei + N_EDGES;
    const float* Wgcn = (const float*)d_in[3];
    const float* Wss = (const float*)d_in[4];
    const float* Wsn = (const float*)d_in[5];
    const float* Wgin = (const float*)d_in[6];
    const float* Wgat = (const float*)d_in[7];
    const float* a_src = (const float*)d_in[8];
    const float* a_dst = (const float*)d_in[9];
    float* out = (float*)d_out;

    const size_t N = N_NODES;
    const size_t E = N_EDGES;
    char* p = (char*)d_ws;
    unsigned int* xh = (unsigned int*)p;  // [(N+1)*32]
    p += (N + 1) * 32 * sizeof(unsigned int);
    int* slot = (int*)p;  // [E]
    p += E * sizeof(int);
    int* srt = (int*)p;  // [E + 3N + 64]
    p += (E + 3 * N + 64) * sizeof(int);
    float2* scal2 = (float2*)p;  // [N+1] {alpha_s, dinv}
    p += (N + 1) * sizeof(float2);
    float* alpha_d = (float*)p;  // [N]
    p += N * sizeof(float);
    int* ncnt = (int*)p;  // [N] (zeroed)
    p += N * sizeof(int);
    int* off = (int*)p;  // [N+1]
    p += (N + 1) * sizeof(int);
    int4* hdr4 = (int4*)p;  // [N]
    p += N * sizeof(int4);
    unsigned int* aggN = (unsigned int*)p;  // [N*32]
    p += N * 32 * sizeof(unsigned int);
    unsigned int* aggG = (unsigned int*)p;  // [N*32]
    p += N * 32 * sizeof(unsigned int);
    unsigned int* aggA = (unsigned int*)p;  // [N*32]
    p += N * 32 * sizeof(unsigned int);
    float* aggD = (float*)p;  // [N]
    p += N * sizeof(float);
    int* bsum = (int*)p;  // [SCAN_BLOCKS]
    p += SCAN_BLOCKS * sizeof(int);
    int* bbase = (int*)p;  // [SCAN_BLOCKS]

    const int E4 = N_EDGES / 4;

    hipMemsetAsync(ncnt, 0, N * sizeof(int), stream);

    k_pack<<<1024, 256, 0, stream>>>((const float2*)x, Wgat, a_src, a_dst, xh,
                                     scal2, alpha_d, N_NODES);
    k_degree<<<(E4 + 255) / 256, 256, 0, stream>>>((const int4*)dst, ncnt,
                                                   (int4*)slot, E4);
    k_scan_part<<<SCAN_BLOCKS, SCAN_T, 0, stream>>>(ncnt, bsum, N_NODES);
    k_scan_base<<<1, SCAN_BLOCKS, 0, stream>>>(bsum, bbase);
    k_scan_chunk<<<SCAN_BLOCKS, SCAN_T, 0, stream>>>(ncnt, bbase, alpha_d, off,
                                                     scal2, hdr4, srt, N_NODES);
    k_scatter<<<(E4 + 255) / 256, 256, 0, stream>>>(
        (const int4*)src, (const int4*)dst, (const int4*)slot, off, srt, E4);
    k_agg<<<1024, 1024, 0, stream>>>(xh, scal2, hdr4, srt, aggN, aggG, aggA,
                                     aggD, N_NODES);
    k_finalize<<<1024, 512, 0, stream>>>((const float2*)x, aggN, aggG, aggA,
                                         aggD, scal2, hdr4, Wgcn, Wss, Wsn,
                                         Wgin, Wgat, wts, out, N_NODES);
}

// Round 7
// 217.916 us; speedup vs baseline: 6.1144x; 1.3429x over previous
//
#include <hip/hip_runtime.h>
#include <hip/hip_fp16.h>

#define N_NODES 100000
#define N_EDGES 1600000
#define DIM 64
#define NEG_SLOPE 0.2f
#define SCAN_BLOCKS 128
#define SCAN_T 256

__device__ __forceinline__ float elu_f(float v) {
    return v > 0.f ? v : (__expf(v) - 1.f);
}
__device__ __forceinline__ float leaky_f(float v) {
    return v > 0.f ? v : NEG_SLOPE * v;
}
__device__ __forceinline__ int pad4(int v) { return (v + 3) & ~3; }

__device__ __forceinline__ unsigned int pkh2(float a, float b) {
    __half2 h = __floats2half2_rn(a, b);
    return *(unsigned int*)&h;
}
__device__ __forceinline__ float2 uph2(unsigned int u) {
    __half2 h = *(__half2*)&u;
    return __half22float2(h);
}

typedef _Float16 f16x8 __attribute__((ext_vector_type(8)));
typedef float f32x4 __attribute__((ext_vector_type(4)));

__device__ __forceinline__ f16x8 u4_to_f16x8(uint4 u) {
    f16x8 r;
    __builtin_memcpy(&r, &u, 16);
    return r;
}

// ---- K1: pack x -> half2; alphas via dot with v_src/v_dst; block0: dummy node;
//          block1: prepack 5 weight matrices into MFMA B-fragment layout ----
__global__ void __launch_bounds__(256) k_pack(
    const float2* __restrict__ xf2, const float* __restrict__ Wgcn,
    const float* __restrict__ Wss, const float* __restrict__ Wsn,
    const float* __restrict__ Wgin, const float* __restrict__ Wgat,
    const float* __restrict__ a_src, const float* __restrict__ a_dst,
    unsigned int* __restrict__ xh, float2* __restrict__ scal2,
    float* __restrict__ alpha_d, unsigned int* __restrict__ wpk, int N) {
    __shared__ float svs[64], svd[64];
    if (threadIdx.x < 64) {
        int t = threadIdx.x;
        float vs = 0.f, vd = 0.f;
        for (int j = 0; j < 64; j++) {
            float w = Wgat[t * 64 + j];
            vs = fmaf(w, a_src[j], vs);
            vd = fmaf(w, a_dst[j], vd);
        }
        svs[t] = vs;
        svd[t] = vd;
    }
    __syncthreads();

    if (blockIdx.x == 0) {
        if (threadIdx.x < 32) xh[(size_t)N * 32 + threadIdx.x] = 0u;
        if (threadIdx.x == 32) scal2[N] = make_float2(-1e30f, 0.f);
    }
    if (blockIdx.x == 1) {
        // wpk[idx], idx = (((m*2+ks)*4+ct)*64+lane)*4+jp
        for (int idx = threadIdx.x; idx < 10240; idx += 256) {
            int jp = idx & 3;
            int lane = (idx >> 2) & 63;
            int ct = (idx >> 8) & 3;
            int mks = idx >> 10;
            int m = mks >> 1, ks = mks & 1;
            int k = ks * 32 + ((lane >> 4) << 3) + jp * 2;
            int col = ct * 16 + (lane & 15);
            const float* Wm = (m == 0)   ? Wgcn
                              : (m == 1) ? Wss
                              : (m == 2) ? Wsn
                              : (m == 3) ? Wgin
                                         : Wgat;
            wpk[idx] = pkh2(Wm[k * 64 + col], Wm[(k + 1) * 64 + col]);
        }
    }

    const int lane = threadIdx.x & 63;
    const int wv = threadIdx.x >> 6;
    const int c = lane & 31;
    const int g = lane >> 5;
    const int npairs = N / 2;

    for (int pr = blockIdx.x * 4 + wv; pr < npairs; pr += gridDim.x * 4) {
        int n = pr * 2 + g;
        float2 x2 = xf2[(size_t)n * 32 + c];
        xh[(size_t)n * 32 + c] = pkh2(x2.x, x2.y);
        float ps = x2.x * svs[2 * c] + x2.y * svs[2 * c + 1];
        float pd = x2.x * svd[2 * c] + x2.y * svd[2 * c + 1];
#pragma unroll
        for (int m = 16; m; m >>= 1) {
            ps += __shfl_xor(ps, m, 32);
            pd += __shfl_xor(pd, m, 32);
        }
        if (c == 0) {
            scal2[n].x = ps;
            alpha_d[n] = pd;
        }
    }
}

// ---- K2: degree count + per-edge slot (int4 vectorized) ----
__global__ void __launch_bounds__(256) k_degree(const int4* __restrict__ dst4,
                                                int* __restrict__ ncnt,
                                                int4* __restrict__ slot4,
                                                int E4) {
    int i = blockIdx.x * blockDim.x + threadIdx.x;
    int stride = gridDim.x * blockDim.x;
    for (; i < E4; i += stride) {
        int4 d = dst4[i];
        int4 s;
        s.x = atomicAdd(&ncnt[d.x], 1);
        s.y = atomicAdd(&ncnt[d.y], 1);
        s.z = atomicAdd(&ncnt[d.z], 1);
        s.w = atomicAdd(&ncnt[d.w], 1);
        slot4[i] = s;
    }
}

// ---- K3a: per-chunk sums of padded counts ----
__global__ void __launch_bounds__(SCAN_T) k_scan_part(
    const int* __restrict__ ncnt, int* __restrict__ bsum, int N) {
    __shared__ int red[SCAN_T];
    const int chunk = (N + SCAN_BLOCKS - 1) / SCAN_BLOCKS;
    const int beg = blockIdx.x * chunk;
    const int end = min(beg + chunk, N);
    int s = 0;
    for (int i = beg + threadIdx.x; i < end; i += SCAN_T) s += pad4(ncnt[i]);
    red[threadIdx.x] = s;
    __syncthreads();
    for (int d = SCAN_T / 2; d; d >>= 1) {
        if (threadIdx.x < d) red[threadIdx.x] += red[threadIdx.x + d];
        __syncthreads();
    }
    if (threadIdx.x == 0) bsum[blockIdx.x] = red[0];
}

// ---- K3b: exclusive scan of chunk sums ----
__global__ void __launch_bounds__(SCAN_BLOCKS) k_scan_base(
    const int* __restrict__ bsum, int* __restrict__ bbase) {
    __shared__ int t[SCAN_BLOCKS];
    int tid = threadIdx.x;
    int v = bsum[tid];
    t[tid] = v;
    __syncthreads();
    for (int d = 1; d < SCAN_BLOCKS; d <<= 1) {
        int u = (tid >= d) ? t[tid - d] : 0;
        __syncthreads();
        t[tid] += u;
        __syncthreads();
    }
    bbase[tid] = t[tid] - v;
}

// ---- K3c: per-chunk exclusive scan -> off[] + node header + dinv + pad fill ----
__global__ void __launch_bounds__(SCAN_T) k_scan_chunk(
    const int* __restrict__ ncnt, const int* __restrict__ bbase,
    const float* __restrict__ alpha_d, int* __restrict__ off,
    float2* __restrict__ scal2, int4* __restrict__ hdr4, int* __restrict__ srt,
    int N) {
    __shared__ int tmp[SCAN_T];
    const int chunk = (N + SCAN_BLOCKS - 1) / SCAN_BLOCKS;
    const int beg = blockIdx.x * chunk;
    const int end = min(beg + chunk, N);
    int base = bbase[blockIdx.x];
    for (int t0 = beg; t0 < end; t0 += SCAN_T) {
        int i = t0 + threadIdx.x;
        int cnt = (i < end) ? ncnt[i] : 0;
        int v = pad4(cnt);
        tmp[threadIdx.x] = v;
        __syncthreads();
        for (int d = 1; d < SCAN_T; d <<= 1) {
            int u = (threadIdx.x >= d) ? tmp[threadIdx.x - d] : 0;
            __syncthreads();
            tmp[threadIdx.x] += u;
            __syncthreads();
        }
        if (i < end) {
            int pos = base + tmp[threadIdx.x] - v;
            off[i] = pos;
            float dv = rsqrtf((float)(cnt + 1));
            scal2[i].y = dv;
            hdr4[i] = make_int4(pos, cnt, __float_as_int(alpha_d[i]),
                                __float_as_int(dv));
            for (int t = cnt; t < v; t++) srt[pos + t] = N_NODES;
        }
        base += tmp[SCAN_T - 1];
        __syncthreads();
    }
}

// ---- K4: scatter src into CSR order (no atomics) ----
__global__ void __launch_bounds__(256) k_scatter(
    const int4* __restrict__ src4, const int4* __restrict__ dst4,
    const int4* __restrict__ slot4, const int* __restrict__ off,
    int* __restrict__ srt, int E4) {
    int i = blockIdx.x * blockDim.x + threadIdx.x;
    int stride = gridDim.x * blockDim.x;
    for (; i < E4; i += stride) {
        int4 s = src4[i];
        int4 d = dst4[i];
        int4 sl = slot4[i];
        srt[off[d.x] + sl.x] = s.x;
        srt[off[d.y] + sl.y] = s.y;
        srt[off[d.z] + sl.z] = s.z;
        srt[off[d.w] + sl.w] = s.w;
    }
}

// ---- K5: aggregation only. wave per node, 8 edges/iter, half2 features ----
__global__ void __launch_bounds__(1024) k_agg(
    const unsigned int* __restrict__ xh, const float2* __restrict__ scal2,
    const int4* __restrict__ hdr4, const int* __restrict__ srt,
    unsigned int* __restrict__ aggN, unsigned int* __restrict__ aggG,
    unsigned int* __restrict__ aggA, float* __restrict__ aggD, int N) {
    __shared__ int sSl[16][64];
    __shared__ float2 sED[16][64];

    const int lane = threadIdx.x & 63;
    const int w = threadIdx.x >> 6;
    const int c = lane & 31;
    const int hf = lane >> 5;
    const int wid = blockIdx.x * 16 + w;
    const int nw = gridDim.x * 16;

    for (int n = wid; n < N; n += nw) {
        const int4 h = hdr4[n];
        const int off0 = h.x;
        const int pdeg = pad4(h.y);
        const float ad = __int_as_float(h.z);

        float2 an = {0.f, 0.f}, ag = {0.f, 0.f}, aa = {0.f, 0.f};
        float den = 0.f;

        for (int c0 = 0; c0 < pdeg; c0 += 64) {
            int idx = c0 + lane;
            int sl = (idx < pdeg) ? srt[off0 + idx] : N_NODES;
            float2 sc = scal2[sl];
            float ee = __expf(leaky_f(sc.x + ad));
            den += ee;
            sSl[w][lane] = sl;
            sED[w][lane] = make_float2(ee, sc.y);
            int jmax = min(64, pdeg - c0);  // multiple of 4
            int j = 0;
            for (; j + 8 <= jmax; j += 8) {
                int b0 = j + hf, b1 = b0 + 2, b2 = b0 + 4, b3 = b0 + 6;
                int s0 = sSl[w][b0], s1 = sSl[w][b1];
                int s2 = sSl[w][b2], s3 = sSl[w][b3];
                float2 e0 = sED[w][b0], e1 = sED[w][b1];
                float2 e2 = sED[w][b2], e3 = sED[w][b3];
                unsigned int u0 = xh[(size_t)s0 * 32 + c];
                unsigned int u1 = xh[(size_t)s1 * 32 + c];
                unsigned int u2 = xh[(size_t)s2 * 32 + c];
                unsigned int u3 = xh[(size_t)s3 * 32 + c];
                float2 f0 = uph2(u0), f1 = uph2(u1);
                float2 f2 = uph2(u2), f3 = uph2(u3);
                an.x += (f0.x + f1.x) + (f2.x + f3.x);
                an.y += (f0.y + f1.y) + (f2.y + f3.y);
                ag.x = fmaf(e0.y, f0.x,
                            fmaf(e1.y, f1.x,
                                 fmaf(e2.y, f2.x, fmaf(e3.y, f3.x, ag.x))));
                ag.y = fmaf(e0.y, f0.y,
                            fmaf(e1.y, f1.y,
                                 fmaf(e2.y, f2.y, fmaf(e3.y, f3.y, ag.y))));
                aa.x = fmaf(e0.x, f0.x,
                            fmaf(e1.x, f1.x,
                                 fmaf(e2.x, f2.x, fmaf(e3.x, f3.x, aa.x))));
                aa.y = fmaf(e0.x, f0.y,
                            fmaf(e1.x, f1.y,
                                 fmaf(e2.x, f2.y, fmaf(e3.x, f3.y, aa.y))));
            }
            if (j < jmax) {  // 4-edge tail
                int b0 = j + hf, b1 = b0 + 2;
                int s0 = sSl[w][b0], s1 = sSl[w][b1];
                float2 e0 = sED[w][b0], e1 = sED[w][b1];
                unsigned int u0 = xh[(size_t)s0 * 32 + c];
                unsigned int u1 = xh[(size_t)s1 * 32 + c];
                float2 f0 = uph2(u0), f1 = uph2(u1);
                an.x += f0.x + f1.x;
                an.y += f0.y + f1.y;
                ag.x = fmaf(e0.y, f0.x, fmaf(e1.y, f1.x, ag.x));
                ag.y = fmaf(e0.y, f0.y, fmaf(e1.y, f1.y, ag.y));
                aa.x = fmaf(e0.x, f0.x, fmaf(e1.x, f1.x, aa.x));
                aa.y = fmaf(e0.x, f0.y, fmaf(e1.x, f1.y, aa.y));
            }
        }

        an.x += __shfl_xor(an.x, 32, 64);
        an.y += __shfl_xor(an.y, 32, 64);
        ag.x += __shfl_xor(ag.x, 32, 64);
        ag.y += __shfl_xor(ag.y, 32, 64);
        aa.x += __shfl_xor(aa.x, 32, 64);
        aa.y += __shfl_xor(aa.y, 32, 64);
#pragma unroll
        for (int m = 32; m; m >>= 1) den += __shfl_xor(den, m, 64);

        if (lane < 32) {
            size_t o = (size_t)n * 32 + c;
            aggN[o] = pkh2(an.x, an.y);
            aggG[o] = pkh2(ag.x, ag.y);
            aggA[o] = pkh2(aa.x, aa.y);
        }
        if (lane == 0) aggD[n] = den;
    }
}

// ---- K6: MFMA finalize. wave per 16-node tile; 5 GEMVs as 16x16x32 MFMAs ----
__global__ void __launch_bounds__(256) k_finalize(
    const float4* __restrict__ xf4, const uint4* __restrict__ aggN4,
    const uint4* __restrict__ aggG4, const uint4* __restrict__ aggA4,
    const float* __restrict__ aggD, const float2* __restrict__ scal2,
    const int4* __restrict__ hdr4, const uint4* __restrict__ wpk4,
    const float* __restrict__ wts, float* __restrict__ out, int NT) {
    __shared__ uint4 sB[2560];  // 40KB: B-frags [(m*2+ks)*4+ct][lane]
    for (int i = threadIdx.x; i < 2560; i += 256) sB[i] = wpk4[i];
    __syncthreads();

    const int lane = threadIdx.x & 63;
    const int wv = threadIdx.x >> 6;
    const int kg = lane >> 4;   // k-group 0..3
    const int nl = lane & 15;   // A-row (node in tile)
    const float w0 = wts[0], w1 = wts[1], w2 = wts[2], w3 = wts[3];

    for (int t = blockIdx.x * 4 + wv; t < NT; t += gridDim.x * 4) {
        const int n = t * 16 + nl;
        const int4 h = hdr4[n];
        const float ad = __int_as_float(h.z);
        const float dv = __int_as_float(h.w);
        const float as = scal2[n].x;
        const float den = aggD[n];
        const float ee_s = __expf(leaky_f(as + ad));
        const float dent = den + ee_s;
        const float icnt = 1.f / fmaxf((float)h.y, 1.f);
        const float dv2 = dv * dv;

        // build A-fragments in registers: lane covers k = ks*32 + kg*8 + 0..7
        unsigned int fa[5][2][4];
#pragma unroll
        for (int ks = 0; ks < 2; ks++) {
            uint4 uN = aggN4[(size_t)n * 8 + ks * 4 + kg];
            uint4 uG = aggG4[(size_t)n * 8 + ks * 4 + kg];
            uint4 uA = aggA4[(size_t)n * 8 + ks * 4 + kg];
            float4 x0 = xf4[(size_t)n * 16 + ks * 8 + kg * 2];
            float4 x1 = xf4[(size_t)n * 16 + ks * 8 + kg * 2 + 1];
            float xs[8] = {x0.x, x0.y, x0.z, x0.w, x1.x, x1.y, x1.z, x1.w};
            unsigned int un[4] = {uN.x, uN.y, uN.z, uN.w};
            unsigned int ug[4] = {uG.x, uG.y, uG.z, uG.w};
            unsigned int ua[4] = {uA.x, uA.y, uA.z, uA.w};
#pragma unroll
            for (int c4 = 0; c4 < 4; c4++) {
                float xx = xs[2 * c4], xy = xs[2 * c4 + 1];
                float2 nn = uph2(un[c4]);
                float2 gg = uph2(ug[c4]);
                float2 av = uph2(ua[c4]);
                fa[0][ks][c4] = pkh2(fmaf(dv, gg.x, dv2 * xx),
                                     fmaf(dv, gg.y, dv2 * xy));   // GCN
                fa[1][ks][c4] = pkh2(xx, xy);                     // x (Wss)
                fa[2][ks][c4] = pkh2(nn.x * icnt, nn.y * icnt);   // nmean
                fa[3][ks][c4] = pkh2(xx + nn.x, xy + nn.y);       // GIN
                fa[4][ks][c4] = pkh2(fmaf(ee_s, xx, av.x) / dent,
                                     fmaf(ee_s, xy, av.y) / dent);  // GAT
            }
        }
        f16x8 A[5][2];
#pragma unroll
        for (int m = 0; m < 5; m++)
#pragma unroll
            for (int ks = 0; ks < 2; ks++) {
                uint4 u = make_uint4(fa[m][ks][0], fa[m][ks][1], fa[m][ks][2],
                                     fa[m][ks][3]);
                A[m][ks] = u4_to_f16x8(u);
            }

        float res[4][4];
        const f32x4 zero = {0.f, 0.f, 0.f, 0.f};
#pragma unroll
        for (int ct = 0; ct < 4; ct++) {
            // GCN
            f32x4 acc = __builtin_amdgcn_mfma_f32_16x16x32_f16(
                A[0][0], u4_to_f16x8(sB[(0 * 4 + ct) * 64 + lane]), zero, 0, 0,
                0);
            acc = __builtin_amdgcn_mfma_f32_16x16x32_f16(
                A[0][1], u4_to_f16x8(sB[(1 * 4 + ct) * 64 + lane]), acc, 0, 0,
                0);
#pragma unroll
            for (int r = 0; r < 4; r++) res[ct][r] = w0 * elu_f(acc[r]);
            // SAGE = x@Wss + nmean@Wsn (chained C)
            acc = __builtin_amdgcn_mfma_f32_16x16x32_f16(
                A[1][0], u4_to_f16x8(sB[(2 * 4 + ct) * 64 + lane]), zero, 0, 0,
                0);
            acc = __builtin_amdgcn_mfma_f32_16x16x32_f16(
                A[1][1], u4_to_f16x8(sB[(3 * 4 + ct) * 64 + lane]), acc, 0, 0,
                0);
            acc = __builtin_amdgcn_mfma_f32_16x16x32_f16(
                A[2][0], u4_to_f16x8(sB[(4 * 4 + ct) * 64 + lane]), acc, 0, 0,
                0);
            acc = __builtin_amdgcn_mfma_f32_16x16x32_f16(
                A[2][1], u4_to_f16x8(sB[(5 * 4 + ct) * 64 + lane]), acc, 0, 0,
                0);
#pragma unroll
            for (int r = 0; r < 4; r++) res[ct][r] += w1 * elu_f(acc[r]);
            // GIN
            acc = __builtin_amdgcn_mfma_f32_16x16x32_f16(
                A[3][0], u4_to_f16x8(sB[(6 * 4 + ct) * 64 + lane]), zero, 0, 0,
                0);
            acc = __builtin_amdgcn_mfma_f32_16x16x32_f16(
                A[3][1], u4_to_f16x8(sB[(7 * 4 + ct) * 64 + lane]), acc, 0, 0,
                0);
#pragma unroll
            for (int r = 0; r < 4; r++) res[ct][r] += w2 * elu_f(acc[r]);
            // GAT
            acc = __builtin_amdgcn_mfma_f32_16x16x32_f16(
                A[4][0], u4_to_f16x8(sB[(8 * 4 + ct) * 64 + lane]), zero, 0, 0,
                0);
            acc = __builtin_amdgcn_mfma_f32_16x16x32_f16(
                A[4][1], u4_to_f16x8(sB[(9 * 4 + ct) * 64 + lane]), acc, 0, 0,
                0);
#pragma unroll
            for (int r = 0; r < 4; r++) res[ct][r] += w3 * elu_f(acc[r]);
        }

        // C/D layout: col(feature)=lane&15, row(node)=kg*4+r
#pragma unroll
        for (int ct = 0; ct < 4; ct++)
#pragma unroll
            for (int r = 0; r < 4; r++) {
                int node = t * 16 + kg * 4 + r;
                out[(size_t)node * 64 + ct * 16 + nl] = res[ct][r];
            }
    }
}

extern "C" void kernel_launch(void* const* d_in, const int* in_sizes, int n_in,
                              void* d_out, int out_size, void* d_ws,
                              size_t ws_size, hipStream_t stream) {
    const float* x = (const float*)d_in[0];
    const float* wts = (const float*)d_in[1];
    const int* ei = (const int*)d_in[2];  // int32 (jax x64 disabled)
    const int* src = ei;
    const int* dst = ei + N_EDGES;
    const float* Wgcn = (const float*)d_in[3];
    const float* Wss = (const float*)d_in[4];
    const float* Wsn = (const float*)d_in[5];
    const float* Wgin = (const float*)d_in[6];
    const float* Wgat = (const float*)d_in[7];
    const float* a_src = (const float*)d_in[8];
    const float* a_dst = (const float*)d_in[9];
    float* out = (float*)d_out;

    const size_t N = N_NODES;
    const size_t E = N_EDGES;
    char* p = (char*)d_ws;
    unsigned int* xh = (unsigned int*)p;  // [(N+1)*32]
    p += (N + 1) * 32 * sizeof(unsigned int);
    int* slot = (int*)p;  // [E]
    p += E * sizeof(int);
    int* srt = (int*)p;  // [E + 3N + 64]
    p += (E + 3 * N + 64) * sizeof(int);
    float2* scal2 = (float2*)p;  // [N+1] {alpha_s, dinv}
    p += (N + 1) * sizeof(float2);
    float* alpha_d = (float*)p;  // [N]
    p += N * sizeof(float);
    int* ncnt = (int*)p;  // [N] (zeroed)
    p += N * sizeof(int);
    int* off = (int*)p;  // [N+1]
    p += (N + 1) * sizeof(int);
    int4* hdr4 = (int4*)p;  // [N]
    p += N * sizeof(int4);
    unsigned int* aggN = (unsigned int*)p;  // [N*32]
    p += N * 32 * sizeof(unsigned int);
    unsigned int* aggG = (unsigned int*)p;  // [N*32]
    p += N * 32 * sizeof(unsigned int);
    unsigned int* aggA = (unsigned int*)p;  // [N*32]
    p += N * 32 * sizeof(unsigned int);
    float* aggD = (float*)p;  // [N]
    p += N * sizeof(float);
    int* bsum = (int*)p;  // [SCAN_BLOCKS]
    p += SCAN_BLOCKS * sizeof(int);
    int* bbase = (int*)p;  // [SCAN_BLOCKS]
    p += SCAN_BLOCKS * sizeof(int);
    unsigned int* wpk = (unsigned int*)p;  // [10240] packed B-frags
    p += 10240 * sizeof(unsigned int);

    const int E4 = N_EDGES / 4;

    hipMemsetAsync(ncnt, 0, N * sizeof(int), stream);

    k_pack<<<1024, 256, 0, stream>>>((const float2*)x, Wgcn, Wss, Wsn, Wgin,
                                     Wgat, a_src, a_dst, xh, scal2, alpha_d,
                                     wpk, N_NODES);
    k_degree<<<(E4 + 255) / 256, 256, 0, stream>>>((const int4*)dst, ncnt,
                                                   (int4*)slot, E4);
    k_scan_part<<<SCAN_BLOCKS, SCAN_T, 0, stream>>>(ncnt, bsum, N_NODES);
    k_scan_base<<<1, SCAN_BLOCKS, 0, stream>>>(bsum, bbase);
    k_scan_chunk<<<SCAN_BLOCKS, SCAN_T, 0, stream>>>(ncnt, bbase, alpha_d, off,
                                                     scal2, hdr4, srt, N_NODES);
    k_scatter<<<(E4 + 255) / 256, 256, 0, stream>>>(
        (const int4*)src, (const int4*)dst, (const int4*)slot, off, srt, E4);
    k_agg<<<1024, 1024, 0, stream>>>(xh, scal2, hdr4, srt, aggN, aggG, aggA,
                                     aggD, N_NODES);
    k_finalize<<<512, 256, 0, stream>>>(
        (const float4*)x, (const uint4*)aggN, (const uint4*)aggG,
        (const uint4*)aggA, aggD, scal2, hdr4, (const uint4*)wpk, wts, out,
        N_NODES / 16);
}